// Round 6
// baseline (1067.880 us; speedup 1.0000x reference)
//
#include <hip/hip_runtime.h>
#include <hip/hip_bf16.h>

// GAT 3-layer + pool + dense head for MI355X (gfx950).
// R2: k_agg 16-lanes-per-node; k_ald folded into GEMM; ale layer-major.
// R3-R6: MLP probes (unroll / sched_barrier / asm pin). Net: codegen changed
// (VGPR 80->64, occ 28->37%) but BW pinned at 3.5 TB/s. +31% waves = +0% BW
// and identical pinned-cluster shape across L1/2 vs L3 still shows 2x BW gap
// => limiter is per-instruction request geometry, not MLP/TLP.
// R7: lane->byte remap. L1/2 agg now 8 lanes/node x 64B/lane (stride 64B):
// one dwordx4 instruction touches 64 distinct 64B lines (8 lines x 8 groups),
// matching L3's proven-fast geometry (was 32). Plus 1-chunk-ahead prefetch of
// csr/ale/als so the alpha-phase LLC latency hides under the gather loop.
// R8: resubmit of R7 — previous round failed on container infra, no data.

typedef __attribute__((ext_vector_type(8))) short short8;
typedef __attribute__((ext_vector_type(4))) float floatx4;
typedef __attribute__((ext_vector_type(4))) unsigned int uintx4;

#define DEV __device__ __forceinline__

DEV unsigned short f2b(float f) {
  union { float f; unsigned u; } v; v.f = f;
  unsigned r = v.u + 0x7FFFu + ((v.u >> 16) & 1u);  // RNE
  return (unsigned short)(r >> 16);
}
DEV float b2f(unsigned short u) {
  union { unsigned u; float f; } v; v.u = ((unsigned)u) << 16;
  return v.f;
}

// ---------------- CSR build ----------------
__global__ void k_deg(const int* __restrict__ dst, int* __restrict__ deg, int E) {
  int e = blockIdx.x * 256 + threadIdx.x;
  if (e < E) atomicAdd(&deg[dst[e]], 1);
}

// block-local exclusive scan over 1024 elems (256 thr x 4)
__global__ __launch_bounds__(256) void k_scan1(const int* __restrict__ deg,
    int* __restrict__ rowptr, int* __restrict__ bsum, int N) {
  __shared__ int sd[256];
  int b = blockIdx.x, tid = threadIdx.x;
  int i0 = b * 1024 + tid * 4;
  int v[4]; int s = 0;
#pragma unroll
  for (int j = 0; j < 4; j++) { int i = i0 + j; v[j] = (i < N) ? deg[i] : 0; s += v[j]; }
  sd[tid] = s;
  __syncthreads();
  for (int off = 1; off < 256; off <<= 1) {
    int t = (tid >= off) ? sd[tid - off] : 0;
    __syncthreads();
    sd[tid] += t;
    __syncthreads();
  }
  int run = sd[tid] - s;  // exclusive
#pragma unroll
  for (int j = 0; j < 4; j++) { int i = i0 + j; if (i < N) rowptr[i] = run; run += v[j]; }
  if (tid == 255) bsum[b] = sd[255];
}

__global__ __launch_bounds__(256) void k_scan2(int* __restrict__ bsum, int nb) {
  __shared__ int sd[256];
  int tid = threadIdx.x;
  int v = (tid < nb) ? bsum[tid] : 0;
  sd[tid] = v;
  __syncthreads();
  for (int off = 1; off < 256; off <<= 1) {
    int t = (tid >= off) ? sd[tid - off] : 0;
    __syncthreads();
    sd[tid] += t;
    __syncthreads();
  }
  if (tid < nb) bsum[tid] = sd[tid] - v;  // exclusive
}

__global__ __launch_bounds__(256) void k_scan3(int* __restrict__ rowptr,
    int* __restrict__ cursor, const int* __restrict__ bsum, int N, int E) {
  int b = blockIdx.x, tid = threadIdx.x;
  int add = bsum[b];
  int i0 = b * 1024 + tid * 4;
#pragma unroll
  for (int j = 0; j < 4; j++) {
    int i = i0 + j;
    if (i < N) { int r = rowptr[i] + add; rowptr[i] = r; cursor[i] = r; }
  }
  if (b == 0 && tid == 0) rowptr[N] = E;
}

__global__ void k_scatter(const int* __restrict__ src, const int* __restrict__ dst,
    int* __restrict__ cursor, int2* __restrict__ csr, int E) {
  int e = blockIdx.x * 256 + threadIdx.x;
  if (e < E) {
    int d = dst[e];
    int pos = atomicAdd(&cursor[d], 1);
    csr[pos] = make_int2(src[e], e);
  }
}

// ---------------- weight prep ----------------
__global__ void k_wt(const float* __restrict__ W, unsigned short* __restrict__ Wt,
                     int K, int Nout) {
  int idx = blockIdx.x * 256 + threadIdx.x;
  if (idx < K * Nout) {
    int n = idx / K, k = idx - n * K;
    Wt[idx] = f2b(W[(size_t)k * Nout + n]);
  }
}

// Wept[j][c], j = L*4+h (12 rows used, 16 total)
__global__ void k_wep(const float* __restrict__ We1, const float* __restrict__ ae1,
                      const float* __restrict__ We2, const float* __restrict__ ae2,
                      const float* __restrict__ We3, const float* __restrict__ ae3,
                      unsigned short* __restrict__ Wept) {
  int t = blockIdx.x * 256 + threadIdx.x;  // 0..767
  int j = t >> 6, c = t & 63;
  int L = j >> 2, h = j & 3;
  const float* We = (L == 0) ? We1 : (L == 1) ? We2 : We3;
  const float* ae = (L == 0) ? ae1 : (L == 1) ? ae2 : ae3;
  int C = (L == 2) ? 128 : 64;
  int HC = 4 * C;
  float s = 0.f;
  for (int cc = 0; cc < C; cc++) s += We[(size_t)c * HC + h * C + cc] * ae[h * C + cc];
  Wept[j * 64 + c] = f2b(s);
  if (t < 256) {
    int jj = 12 + (t >> 6);
    Wept[jj * 64 + (t & 63)] = 0;
  }
}

// ---------------- GEMM: C[M,Nout] = A[M,K] @ Bt[Nout,K]^T ----------------
// OUT_MODE: 0 = bf16 C; 2 = ale layer-major f32 ([L][EN][4], col=L*4+h, col<12)
// DO_ALD: epilogue also accumulates als/ald (head = n0*4/Nout, uniform per block)
template<bool A_F32, int OUT_MODE, bool DO_ALD>
__global__ __launch_bounds__(256) void k_gemm(const void* __restrict__ Ap,
    const unsigned short* __restrict__ Bt, void* __restrict__ Cp,
    int M, int Nout, int K, int EN,
    const float* __restrict__ a_s, const float* __restrict__ a_d,
    float* __restrict__ als, float* __restrict__ ald) {
  __shared__ unsigned short As[64][40];
  __shared__ unsigned short Bs[64][40];
  const int tid = threadIdx.x;
  const int wave = tid >> 6, lane = tid & 63;
  const int quad = lane >> 4, l16 = lane & 15;
  const int m0 = blockIdx.x * 64, n0 = blockIdx.y * 64;
  const int arow = tid >> 2, acg = (tid & 3) * 8;
  floatx4 acc[4] = {{0,0,0,0},{0,0,0,0},{0,0,0,0},{0,0,0,0}};
  for (int k0 = 0; k0 < K; k0 += 32) {
    {
      int gm = m0 + arow;
      unsigned short tmp[8];
      if (A_F32) {
        const float* Af = (const float*)Ap;
        if (gm < M) {
          const float4* p = (const float4*)(Af + (size_t)gm * K + k0 + acg);
          float4 u0 = p[0], u1 = p[1];
          tmp[0]=f2b(u0.x); tmp[1]=f2b(u0.y); tmp[2]=f2b(u0.z); tmp[3]=f2b(u0.w);
          tmp[4]=f2b(u1.x); tmp[5]=f2b(u1.y); tmp[6]=f2b(u1.z); tmp[7]=f2b(u1.w);
        } else {
#pragma unroll
          for (int j = 0; j < 8; j++) tmp[j] = 0;
        }
      } else {
        const unsigned short* Ab = (const unsigned short*)Ap;
        uint4 u = {0,0,0,0};
        if (gm < M) u = *(const uint4*)(Ab + (size_t)gm * K + k0 + acg);
        *(uint4*)tmp = u;
      }
      *(uint4*)&As[arow][acg] = *(uint4*)tmp;
      int gn = n0 + arow;
      uint4 bv = {0,0,0,0};
      if (gn < Nout) bv = *(const uint4*)(Bt + (size_t)gn * K + k0 + acg);
      *(uint4*)&Bs[arow][acg] = bv;
    }
    __syncthreads();
    short8 a = *(const short8*)&As[wave * 16 + l16][quad * 8];
#pragma unroll
    for (int t = 0; t < 4; t++) {
      short8 b = *(const short8*)&Bs[t * 16 + l16][quad * 8];
      acc[t] = __builtin_amdgcn_mfma_f32_16x16x32_bf16(a, b, acc[t], 0, 0, 0);
    }
    __syncthreads();
  }
#pragma unroll
  for (int t = 0; t < 4; t++) {
#pragma unroll
    for (int r = 0; r < 4; r++) {
      int row = m0 + wave * 16 + quad * 4 + r;  // C/D: col=lane&15, row=quad*4+reg
      int col = n0 + t * 16 + l16;
      float v = acc[t][r];
      if (OUT_MODE == 0) {
        if (row < M && col < Nout)
          ((unsigned short*)Cp)[(size_t)row * Nout + col] = f2b(v);
      } else {  // ale layer-major
        if (row < M && col < 12)
          ((float*)Cp)[((size_t)(col >> 2) * EN + row) * 4 + (col & 3)] = v;
      }
    }
  }
  if constexpr (DO_ALD) {
    int h = (n0 * 4) / Nout;
#pragma unroll
    for (int r = 0; r < 4; r++) {
      float ps = 0.f, pd = 0.f;
#pragma unroll
      for (int t = 0; t < 4; t++) {
        int col = n0 + t * 16 + l16;
        float v = acc[t][r];
        ps += v * a_s[col];
        pd += v * a_d[col];
      }
#pragma unroll
      for (int off = 1; off < 16; off <<= 1) {
        ps += __shfl_xor(ps, off, 64);
        pd += __shfl_xor(pd, off, 64);
      }
      int row = m0 + wave * 16 + quad * 4 + r;
      if (l16 == 0 && row < M) {
        atomicAdd(&als[row * 4 + h], ps);
        atomicAdd(&ald[row * 4 + h], pd);
      }
    }
  }
}

// ---------------- self-loop al_e = mean of incoming al_e ----------------
__global__ void k_loop_ale(const int* __restrict__ rowptr, const int2* __restrict__ csr,
                           float* __restrict__ ale, int N, int E) {
  int n = blockIdx.x * 256 + threadIdx.x;
  if (n >= N) return;
  const size_t EN = (size_t)E + N;
  int s = rowptr[n], e = rowptr[n + 1];
  float a[12];
#pragma unroll
  for (int j = 0; j < 12; j++) a[j] = 0.f;
  for (int p = s; p < e; p++) {
    int eid = csr[p].y;
#pragma unroll
    for (int L = 0; L < 3; L++) {
      float4 v = *(const float4*)(ale + (L * EN + eid) * 4);
      a[L * 4 + 0] += v.x; a[L * 4 + 1] += v.y;
      a[L * 4 + 2] += v.z; a[L * 4 + 3] += v.w;
    }
  }
  float inv = 1.0f / (float)((e - s) > 1 ? (e - s) : 1);
#pragma unroll
  for (int L = 0; L < 3; L++)
    *(float4*)(ale + (L * EN + E + n) * 4) =
        make_float4(a[L*4+0]*inv, a[L*4+1]*inv, a[L*4+2]*inv, a[L*4+3]*inv);
}

// ---------------- CSR online-softmax aggregation ----------------
// LPN lanes per node (8 for HC=256, 16 for HC=512), FPL=32 features/lane:
// every lane reads a contiguous 64B slice at 64B lane-stride, so one dwordx4
// instruction touches 64 distinct cache lines (max request parallelism).
// 1-chunk-ahead prefetch of csr/ale/als hides alpha-phase latency under the
// gather loop. MODE 0: concat+bias+ReLU -> bf16. MODE 1: mean+bias -> f32.
template<int LPN, int MODE>
__global__ __launch_bounds__(256) void k_agg(const unsigned short* __restrict__ hs,
    const int* __restrict__ rowptr, const int2* __restrict__ csr,
    const float* __restrict__ ale,  // layer base, [EN][4]
    const float* __restrict__ als, const float* __restrict__ ald,
    const float* __restrict__ bias, unsigned short* __restrict__ outb,
    float* __restrict__ outf, int N, int E) {
  const int FPL = 32;
  const int HC  = LPN * FPL;   // row width in shorts
  const int NG  = 64 / LPN;    // nodes per wave
  __shared__ float s_w[4][NG][LPN][4];
  __shared__ int   s_s[4][NG][LPN];
  const int wave = threadIdx.x >> 6;
  const int lane = threadIdx.x & 63;
  const int grp  = lane / LPN;
  const int sl   = lane % LPN;
  const int hd   = sl >> (LPN >> 3);  // head owning this lane's feature slice
  const int node = blockIdx.x * (4 * NG) + wave * NG + grp;
  if (node >= N) return;  // no __syncthreads in this kernel
  int start = rowptr[node];
  int cnt   = rowptr[node + 1] - start;
  int total = cnt + 1;  // + self-loop
  const float4 aldv   = *(const float4*)(ald + (size_t)node * 4);
  const float4 selfev = *(const float4*)(ale + ((size_t)E + node) * 4);
  const float4 selfsv = *(const float4*)(als + (size_t)node * 4);
  // prefetch chunk 0's alpha inputs
  int    psidx = node;
  float4 pev = selfev, psv = selfsv;
  if (sl < cnt) {
    int2 se = csr[start + sl];
    psidx = se.x;
    pev = *(const float4*)(ale + (size_t)se.y * 4);
    psv = *(const float4*)(als + (size_t)se.x * 4);
  }
  float m0=-1e30f, m1=-1e30f, m2=-1e30f, m3=-1e30f;
  float d0=0.f, d1=0.f, d2=0.f, d3=0.f;
  float acc[FPL];
#pragma unroll
  for (int j = 0; j < FPL; j++) acc[j] = 0.f;
  for (int base = 0; base < total; base += LPN) {
    int ei = base + sl;
    bool active = ei < total;
    float a0=-1e30f, a1=-1e30f, a2=-1e30f, a3=-1e30f;
    int sidx = psidx;
    if (active) {
      a0 = psv.x + aldv.x + pev.x;
      a1 = psv.y + aldv.y + pev.y;
      a2 = psv.z + aldv.z + pev.z;
      a3 = psv.w + aldv.w + pev.w;
      a0 = a0 > 0.f ? a0 : 0.2f * a0;
      a1 = a1 > 0.f ? a1 : 0.2f * a1;
      a2 = a2 > 0.f ? a2 : 0.2f * a2;
      a3 = a3 > 0.f ? a3 : 0.2f * a3;
    }
    float c0=a0, c1=a1, c2=a2, c3=a3;
#pragma unroll
    for (int off = LPN / 2; off > 0; off >>= 1) {
      c0 = fmaxf(c0, __shfl_xor(c0, off, 64));
      c1 = fmaxf(c1, __shfl_xor(c1, off, 64));
      c2 = fmaxf(c2, __shfl_xor(c2, off, 64));
      c3 = fmaxf(c3, __shfl_xor(c3, off, 64));
    }
    float n0v = fmaxf(m0, c0), n1v = fmaxf(m1, c1), n2v = fmaxf(m2, c2), n3v = fmaxf(m3, c3);
    float p0 = active ? __expf(a0 - n0v) : 0.f;
    float p1 = active ? __expf(a1 - n1v) : 0.f;
    float p2 = active ? __expf(a2 - n2v) : 0.f;
    float p3 = active ? __expf(a3 - n3v) : 0.f;
    float s0=p0, s1=p1, s2=p2, s3=p3;
#pragma unroll
    for (int off = LPN / 2; off > 0; off >>= 1) {
      s0 += __shfl_xor(s0, off, 64);
      s1 += __shfl_xor(s1, off, 64);
      s2 += __shfl_xor(s2, off, 64);
      s3 += __shfl_xor(s3, off, 64);
    }
    float r0 = __expf(m0 - n0v), r1 = __expf(m1 - n1v);
    float r2 = __expf(m2 - n2v), r3 = __expf(m3 - n3v);
    d0 = d0 * r0 + s0; d1 = d1 * r1 + s1; d2 = d2 * r2 + s2; d3 = d3 * r3 + s3;
    float rh = hd == 0 ? r0 : hd == 1 ? r1 : hd == 2 ? r2 : r3;
#pragma unroll
    for (int j = 0; j < FPL; j++) acc[j] *= rh;
    m0 = n0v; m1 = n1v; m2 = n2v; m3 = n3v;
    *(float4*)&s_w[wave][grp][sl][0] = make_float4(p0, p1, p2, p3);
    s_s[wave][grp][sl] = sidx;
    __threadfence_block();  // per-wave LDS visibility
    // prefetch next chunk's alpha inputs (in flight during gather below)
    if (base + LPN < total) {
      int nei = base + LPN + sl;
      psidx = node; pev = selfev; psv = selfsv;
      if (nei < cnt) {
        int2 se = csr[start + nei];
        psidx = se.x;
        pev = *(const float4*)(ale + (size_t)se.y * 4);
        psv = *(const float4*)(als + (size_t)se.x * 4);
      }
    }
    int chunk = total - base; if (chunk > LPN) chunk = LPN;
    int t = 0;
    // 2 edges x 4 dwordx4 pinned in flight via asm operand list.
    for (; t + 2 <= chunk; t += 2) {
      float w0 = s_w[wave][grp][t][hd];
      float w1 = s_w[wave][grp][t + 1][hd];
      int   q0 = s_s[wave][grp][t];
      int   q1 = s_s[wave][grp][t + 1];
      const uintx4* p0p = (const uintx4*)(hs + (size_t)q0 * HC + sl * FPL);
      const uintx4* p1p = (const uintx4*)(hs + (size_t)q1 * HC + sl * FPL);
      uintx4 v0[4], v1[4];
#pragma unroll
      for (int q = 0; q < 4; q++) v0[q] = p0p[q];
#pragma unroll
      for (int q = 0; q < 4; q++) v1[q] = p1p[q];
      asm volatile("" :: "v"(v0[0]), "v"(v0[1]), "v"(v0[2]), "v"(v0[3]),
                         "v"(v1[0]), "v"(v1[1]), "v"(v1[2]), "v"(v1[3]));
#pragma unroll
      for (int q = 0; q < 4; q++) {
        uintx4 x = v0[q];
#pragma unroll
        for (int k = 0; k < 4; k++) {
          float lo = __uint_as_float(x[k] << 16);
          float hi = __uint_as_float(x[k] & 0xffff0000u);
          acc[q * 8 + k * 2 + 0] += w0 * lo;
          acc[q * 8 + k * 2 + 1] += w0 * hi;
        }
      }
#pragma unroll
      for (int q = 0; q < 4; q++) {
        uintx4 x = v1[q];
#pragma unroll
        for (int k = 0; k < 4; k++) {
          float lo = __uint_as_float(x[k] << 16);
          float hi = __uint_as_float(x[k] & 0xffff0000u);
          acc[q * 8 + k * 2 + 0] += w1 * lo;
          acc[q * 8 + k * 2 + 1] += w1 * hi;
        }
      }
    }
    if (t < chunk) {
      float w0 = s_w[wave][grp][t][hd];
      int   q0 = s_s[wave][grp][t];
      const uintx4* p0p = (const uintx4*)(hs + (size_t)q0 * HC + sl * FPL);
      uintx4 v0[4];
#pragma unroll
      for (int q = 0; q < 4; q++) v0[q] = p0p[q];
#pragma unroll
      for (int q = 0; q < 4; q++) {
        uintx4 x = v0[q];
#pragma unroll
        for (int k = 0; k < 4; k++) {
          float lo = __uint_as_float(x[k] << 16);
          float hi = __uint_as_float(x[k] & 0xffff0000u);
          acc[q * 8 + k * 2 + 0] += w0 * lo;
          acc[q * 8 + k * 2 + 1] += w0 * hi;
        }
      }
    }
  }
  float dh = hd == 0 ? d0 : hd == 1 ? d1 : hd == 2 ? d2 : d3;
  float inv = 1.0f / (dh + 1e-16f);
  if constexpr (MODE == 0) {
    unsigned short tmp[FPL];
#pragma unroll
    for (int j = 0; j < FPL; j++) {
      float v = acc[j] * inv + bias[sl * FPL + j];
      tmp[j] = f2b(fmaxf(v, 0.f));
    }
    unsigned short* op = outb + (size_t)node * HC + sl * FPL;
#pragma unroll
    for (int q = 0; q < 4; q++) ((uint4*)op)[q] = ((uint4*)tmp)[q];
  } else {
    // mean over heads (LPN=16): lane sl covers hs cols [sl*32, sl*32+32);
    // head=sl>>2, out col c = (sl&3)*32 + j. Sum lanes sl^4, sl^8.
#pragma unroll
    for (int j = 0; j < FPL; j++) {
      float v = acc[j] * inv;
      v += __shfl_xor(v, 4, 64);
      v += __shfl_xor(v, 8, 64);
      acc[j] = v * 0.25f;
    }
    if (sl < 4) {
      float* op = outf + (size_t)node * (4 * FPL) + sl * FPL;
#pragma unroll
      for (int j = 0; j < FPL; j++) op[j] = acc[j] + bias[sl * FPL + j];
    }
  }
}

// ---------------- pooling (batch is sorted) ----------------
__global__ __launch_bounds__(256) void k_pool(const float* __restrict__ out3,
    const int* __restrict__ bat, float* __restrict__ g, int* __restrict__ cntb, int N) {
  int wid = blockIdx.x * 4 + (threadIdx.x >> 6);
  int lane = threadIdx.x & 63;
  int per = (N + 255) / 256;
  int s = wid * per, e = s + per;
  if (e > N) e = N;
  if (s >= e) return;
  int cur = bat[s];
  float ax = 0.f, ay = 0.f; int run = 0;
  for (int n = s; n < e; n++) {
    int b = bat[n];
    if (b != cur) {
      atomicAdd(&g[cur * 128 + lane * 2], ax);
      atomicAdd(&g[cur * 128 + lane * 2 + 1], ay);
      if (lane == 0) atomicAdd(&cntb[cur], run);
      ax = 0.f; ay = 0.f; run = 0; cur = b;
    }
    float2 v = *(const float2*)(out3 + (size_t)n * 128 + lane * 2);
    ax += v.x; ay += v.y; run++;
  }
  atomicAdd(&g[cur * 128 + lane * 2], ax);
  atomicAdd(&g[cur * 128 + lane * 2 + 1], ay);
  if (lane == 0) atomicAdd(&cntb[cur], run);
}

// ---------------- final head ----------------
__global__ __launch_bounds__(320) void k_final(const float* __restrict__ g,
    const int* __restrict__ cntb, const float* __restrict__ Wa, const float* __restrict__ ba,
    const float* __restrict__ Wv, const float* __restrict__ bv, float* __restrict__ out) {
  __shared__ float gm[128];
  int b = blockIdx.x, t = threadIdx.x;
  if (t < 128) {
    float c = (float)cntb[b];
    gm[t] = g[b * 128 + t] / fmaxf(c, 1.f);
  }
  __syncthreads();
  if (t < 257) {
    float acc = 0.f;
    if (t < 256) {
      for (int k = 0; k < 128; k++) acc += gm[k] * Wa[k * 256 + t];
      acc += ba[t];
    } else {
      for (int k = 0; k < 128; k++) acc += gm[k] * Wv[k];
      acc += bv[0];
    }
    out[b * 257 + t] = acc;
  }
}

extern "C" void kernel_launch(void* const* d_in, const int* in_sizes, int n_in,
                              void* d_out, int out_size, void* d_ws, size_t ws_size,
                              hipStream_t stream) {
  const float* x   = (const float*)d_in[0];
  const int*   ei  = (const int*)  d_in[1];
  const float* ea  = (const float*)d_in[2];
  const int*   bat = (const int*)  d_in[3];
  const float* W1  = (const float*)d_in[4];
  const float* as1 = (const float*)d_in[5];
  const float* ad1 = (const float*)d_in[6];
  const float* We1 = (const float*)d_in[7];
  const float* ae1 = (const float*)d_in[8];
  const float* b1  = (const float*)d_in[9];
  const float* W2  = (const float*)d_in[10];
  const float* as2 = (const float*)d_in[11];
  const float* ad2 = (const float*)d_in[12];
  const float* We2 = (const float*)d_in[13];
  const float* ae2 = (const float*)d_in[14];
  const float* b2  = (const float*)d_in[15];
  const float* W3  = (const float*)d_in[16];
  const float* as3 = (const float*)d_in[17];
  const float* ad3 = (const float*)d_in[18];
  const float* We3 = (const float*)d_in[19];
  const float* ae3 = (const float*)d_in[20];
  const float* b3  = (const float*)d_in[21];
  const float* Wa  = (const float*)d_in[22];
  const float* ba  = (const float*)d_in[23];
  const float* Wv  = (const float*)d_in[24];
  const float* bv  = (const float*)d_in[25];
  (void)n_in; (void)out_size; (void)ws_size;

  const int N = in_sizes[0] / 192;  // 50000
  const int E = in_sizes[1] / 2;    // 800000
  const size_t EN = (size_t)E + N;
  const int* srcv = ei;
  const int* dstv = ei + E;
  const int nb = (N + 1023) / 1024;

  size_t off = 0;
  auto alloc = [&](size_t bytes) -> char* {
    char* p = (char*)d_ws + off;
    off += (bytes + 255) & ~(size_t)255;
    return p;
  };
  int* deg     = (int*)alloc((size_t)N * 4);
  int* rowptr  = (int*)alloc((size_t)(N + 1) * 4);
  int* cursor  = (int*)alloc((size_t)N * 4);
  int* bsum    = (int*)alloc(256 * 4);
  int2* csr    = (int2*)alloc((size_t)E * 8);
  float* ale   = (float*)alloc(3 * EN * 4 * 4);  // [L][EN][4]
  unsigned short* Wept = (unsigned short*)alloc(16 * 64 * 2);
  unsigned short* W1t  = (unsigned short*)alloc(256 * 192 * 2);
  unsigned short* W2t  = (unsigned short*)alloc(256 * 256 * 2);
  unsigned short* W3t  = (unsigned short*)alloc(512 * 256 * 2);
  unsigned short* hs   = (unsigned short*)alloc((size_t)N * 512 * 2);
  unsigned short* h1   = (unsigned short*)alloc((size_t)N * 256 * 2);
  unsigned short* h2   = (unsigned short*)alloc((size_t)N * 256 * 2);
  float* out3  = (float*)alloc((size_t)N * 128 * 4);
  float* als_all = (float*)alloc((size_t)N * 4 * 4 * 6);  // als1,ald1,als2,ald2,als3,ald3
  float* g     = (float*)alloc(64 * 128 * 4 + 64 * 4);
  int* cntb    = (int*)(g + 64 * 128);
  float* als1 = als_all + (size_t)N * 4 * 0;
  float* ald1 = als_all + (size_t)N * 4 * 1;
  float* als2 = als_all + (size_t)N * 4 * 2;
  float* ald2 = als_all + (size_t)N * 4 * 3;
  float* als3 = als_all + (size_t)N * 4 * 4;
  float* ald3 = als_all + (size_t)N * 4 * 5;

  hipMemsetAsync(deg, 0, (size_t)N * 4, stream);
  hipMemsetAsync(als_all, 0, (size_t)N * 4 * 4 * 6, stream);
  hipMemsetAsync(g, 0, 64 * 128 * 4 + 64 * 4, stream);

  k_deg<<<(E + 255) / 256, 256, 0, stream>>>(dstv, deg, E);
  k_scan1<<<nb, 256, 0, stream>>>(deg, rowptr, bsum, N);
  k_scan2<<<1, 256, 0, stream>>>(bsum, nb);
  k_scan3<<<nb, 256, 0, stream>>>(rowptr, cursor, bsum, N, E);
  k_scatter<<<(E + 255) / 256, 256, 0, stream>>>(srcv, dstv, cursor, csr, E);
  k_wt<<<(192 * 256 + 255) / 256, 256, 0, stream>>>(W1, W1t, 192, 256);
  k_wt<<<(256 * 256 + 255) / 256, 256, 0, stream>>>(W2, W2t, 256, 256);
  k_wt<<<(256 * 512 + 255) / 256, 256, 0, stream>>>(W3, W3t, 256, 512);
  k_wep<<<3, 256, 0, stream>>>(We1, ae1, We2, ae2, We3, ae3, Wept);
  // al_e for all 3 layers in one GEMM over edge_attr (layer-major output)
  k_gemm<true, 2, false><<<dim3((E + 63) / 64, 1), 256, 0, stream>>>(
      ea, Wept, ale, E, 16, 64, (int)EN, nullptr, nullptr, nullptr, nullptr);
  k_loop_ale<<<(N + 255) / 256, 256, 0, stream>>>(rowptr, csr, ale, N, E);
  // layer 1
  k_gemm<true, 0, true><<<dim3((N + 63) / 64, 4), 256, 0, stream>>>(
      x, W1t, hs, N, 256, 192, 0, as1, ad1, als1, ald1);
  k_agg<8, 0><<<(N + 31) / 32, 256, 0, stream>>>(
      hs, rowptr, csr, ale + 0 * EN * 4, als1, ald1, b1, h1, nullptr, N, E);
  // layer 2
  k_gemm<false, 0, true><<<dim3((N + 63) / 64, 4), 256, 0, stream>>>(
      h1, W2t, hs, N, 256, 256, 0, as2, ad2, als2, ald2);
  k_agg<8, 0><<<(N + 31) / 32, 256, 0, stream>>>(
      hs, rowptr, csr, ale + 1 * EN * 4, als2, ald2, b2, h2, nullptr, N, E);
  // layer 3
  k_gemm<false, 0, true><<<dim3((N + 63) / 64, 8), 256, 0, stream>>>(
      h2, W3t, hs, N, 512, 256, 0, as3, ad3, als3, ald3);
  k_agg<16, 1><<<(N + 15) / 16, 256, 0, stream>>>(
      hs, rowptr, csr, ale + 2 * EN * 4, als3, ald3, b3, nullptr, out3, N, E);
  // pool + head
  k_pool<<<64, 256, 0, stream>>>(out3, bat, g, cntb, N);
  k_final<<<64, 320, 0, stream>>>(g, cntb, Wa, ba, Wv, bv, (float*)d_out);
}

// Round 7
// 1067.688 us; speedup vs baseline: 1.0002x; 1.0002x over previous
//
#include <hip/hip_runtime.h>
#include <hip/hip_bf16.h>

// GAT 3-layer + pool + dense head for MI355X (gfx950).
// R2: k_agg 16-lanes-per-node; k_ald folded into GEMM; ale layer-major.
// R3-R8: MLP/geometry probes all NULL. Empirical law from 6 rounds of PMC:
// random row-gather rate is capped at ~5.9G rows/s regardless of row size
// (L3 agg: 2x bytes/row in the same 144us). Transaction-bound, not byte/MLP.
// R9: source-bucketed CSR (counting sort by (dst, src>>13), 7 buckets of
// 8192 rows = 4MB = one XCD L2). All agg blocks are co-resident and walk
// buckets in rough lockstep -> active gather window becomes L2-resident.
// k_agg code unchanged; locality lives in the csr data order. FETCH is the
// tell: floor ~8/17 of 472MB (re-read 17x, ~2x per XCD per window).

typedef __attribute__((ext_vector_type(8))) short short8;
typedef __attribute__((ext_vector_type(4))) float floatx4;
typedef __attribute__((ext_vector_type(4))) unsigned int uintx4;

#define DEV __device__ __forceinline__

DEV unsigned short f2b(float f) {
  union { float f; unsigned u; } v; v.f = f;
  unsigned r = v.u + 0x7FFFu + ((v.u >> 16) & 1u);  // RNE
  return (unsigned short)(r >> 16);
}
DEV float b2f(unsigned short u) {
  union { unsigned u; float f; } v; v.u = ((unsigned)u) << 16;
  return v.f;
}

// ---------------- bucketed CSR build ----------------
// deg2[n*8 + b] = #edges into n with src in bucket b (b = src>>13, 0..6).
__global__ void k_deg2(const int* __restrict__ src, const int* __restrict__ dst,
                       int* __restrict__ deg2, int E) {
  int e = blockIdx.x * 256 + threadIdx.x;
  if (e < E) atomicAdd(&deg2[(size_t)dst[e] * 8 + (src[e] >> 13)], 1);
}

// block-local exclusive scan over 1024 elems (256 thr x 4)
__global__ __launch_bounds__(256) void k_scan1(const int* __restrict__ deg,
    int* __restrict__ rowptr, int* __restrict__ bsum, int N) {
  __shared__ int sd[256];
  int b = blockIdx.x, tid = threadIdx.x;
  int i0 = b * 1024 + tid * 4;
  int v[4]; int s = 0;
#pragma unroll
  for (int j = 0; j < 4; j++) { int i = i0 + j; v[j] = (i < N) ? deg[i] : 0; s += v[j]; }
  sd[tid] = s;
  __syncthreads();
  for (int off = 1; off < 256; off <<= 1) {
    int t = (tid >= off) ? sd[tid - off] : 0;
    __syncthreads();
    sd[tid] += t;
    __syncthreads();
  }
  int run = sd[tid] - s;  // exclusive
#pragma unroll
  for (int j = 0; j < 4; j++) { int i = i0 + j; if (i < N) rowptr[i] = run; run += v[j]; }
  if (tid == 255) bsum[b] = sd[255];
}

// scan over up to 512 block sums
__global__ __launch_bounds__(512) void k_scan2(int* __restrict__ bsum, int nb) {
  __shared__ int sd[512];
  int tid = threadIdx.x;
  int v = (tid < nb) ? bsum[tid] : 0;
  sd[tid] = v;
  __syncthreads();
  for (int off = 1; off < 512; off <<= 1) {
    int t = (tid >= off) ? sd[tid - off] : 0;
    __syncthreads();
    sd[tid] += t;
    __syncthreads();
  }
  if (tid < nb) bsum[tid] = sd[tid] - v;  // exclusive
}

__global__ __launch_bounds__(256) void k_scan3(int* __restrict__ rowptr,
    int* __restrict__ cursor, const int* __restrict__ bsum, int N, int E) {
  int b = blockIdx.x, tid = threadIdx.x;
  int add = bsum[b];
  int i0 = b * 1024 + tid * 4;
#pragma unroll
  for (int j = 0; j < 4; j++) {
    int i = i0 + j;
    if (i < N) { int r = rowptr[i] + add; rowptr[i] = r; cursor[i] = r; }
  }
  if (b == 0 && tid == 0) rowptr[N] = E;
}

__global__ void k_scatter(const int* __restrict__ src, const int* __restrict__ dst,
    int* __restrict__ cursor, int2* __restrict__ csr, int E) {
  int e = blockIdx.x * 256 + threadIdx.x;
  if (e < E) {
    int s = src[e], d = dst[e];
    int pos = atomicAdd(&cursor[(size_t)d * 8 + (s >> 13)], 1);
    csr[pos] = make_int2(s, e);
  }
}

// ---------------- weight prep ----------------
__global__ void k_wt(const float* __restrict__ W, unsigned short* __restrict__ Wt,
                     int K, int Nout) {
  int idx = blockIdx.x * 256 + threadIdx.x;
  if (idx < K * Nout) {
    int n = idx / K, k = idx - n * K;
    Wt[idx] = f2b(W[(size_t)k * Nout + n]);
  }
}

// Wept[j][c], j = L*4+h (12 rows used, 16 total)
__global__ void k_wep(const float* __restrict__ We1, const float* __restrict__ ae1,
                      const float* __restrict__ We2, const float* __restrict__ ae2,
                      const float* __restrict__ We3, const float* __restrict__ ae3,
                      unsigned short* __restrict__ Wept) {
  int t = blockIdx.x * 256 + threadIdx.x;  // 0..767
  int j = t >> 6, c = t & 63;
  int L = j >> 2, h = j & 3;
  const float* We = (L == 0) ? We1 : (L == 1) ? We2 : We3;
  const float* ae = (L == 0) ? ae1 : (L == 1) ? ae2 : ae3;
  int C = (L == 2) ? 128 : 64;
  int HC = 4 * C;
  float s = 0.f;
  for (int cc = 0; cc < C; cc++) s += We[(size_t)c * HC + h * C + cc] * ae[h * C + cc];
  Wept[j * 64 + c] = f2b(s);
  if (t < 256) {
    int jj = 12 + (t >> 6);
    Wept[jj * 64 + (t & 63)] = 0;
  }
}

// ---------------- GEMM: C[M,Nout] = A[M,K] @ Bt[Nout,K]^T ----------------
// OUT_MODE: 0 = bf16 C; 2 = ale layer-major f32 ([L][EN][4], col=L*4+h, col<12)
// DO_ALD: epilogue also accumulates als/ald (head = n0*4/Nout, uniform per block)
template<bool A_F32, int OUT_MODE, bool DO_ALD>
__global__ __launch_bounds__(256) void k_gemm(const void* __restrict__ Ap,
    const unsigned short* __restrict__ Bt, void* __restrict__ Cp,
    int M, int Nout, int K, int EN,
    const float* __restrict__ a_s, const float* __restrict__ a_d,
    float* __restrict__ als, float* __restrict__ ald) {
  __shared__ unsigned short As[64][40];
  __shared__ unsigned short Bs[64][40];
  const int tid = threadIdx.x;
  const int wave = tid >> 6, lane = tid & 63;
  const int quad = lane >> 4, l16 = lane & 15;
  const int m0 = blockIdx.x * 64, n0 = blockIdx.y * 64;
  const int arow = tid >> 2, acg = (tid & 3) * 8;
  floatx4 acc[4] = {{0,0,0,0},{0,0,0,0},{0,0,0,0},{0,0,0,0}};
  for (int k0 = 0; k0 < K; k0 += 32) {
    {
      int gm = m0 + arow;
      unsigned short tmp[8];
      if (A_F32) {
        const float* Af = (const float*)Ap;
        if (gm < M) {
          const float4* p = (const float4*)(Af + (size_t)gm * K + k0 + acg);
          float4 u0 = p[0], u1 = p[1];
          tmp[0]=f2b(u0.x); tmp[1]=f2b(u0.y); tmp[2]=f2b(u0.z); tmp[3]=f2b(u0.w);
          tmp[4]=f2b(u1.x); tmp[5]=f2b(u1.y); tmp[6]=f2b(u1.z); tmp[7]=f2b(u1.w);
        } else {
#pragma unroll
          for (int j = 0; j < 8; j++) tmp[j] = 0;
        }
      } else {
        const unsigned short* Ab = (const unsigned short*)Ap;
        uint4 u = {0,0,0,0};
        if (gm < M) u = *(const uint4*)(Ab + (size_t)gm * K + k0 + acg);
        *(uint4*)tmp = u;
      }
      *(uint4*)&As[arow][acg] = *(uint4*)tmp;
      int gn = n0 + arow;
      uint4 bv = {0,0,0,0};
      if (gn < Nout) bv = *(const uint4*)(Bt + (size_t)gn * K + k0 + acg);
      *(uint4*)&Bs[arow][acg] = bv;
    }
    __syncthreads();
    short8 a = *(const short8*)&As[wave * 16 + l16][quad * 8];
#pragma unroll
    for (int t = 0; t < 4; t++) {
      short8 b = *(const short8*)&Bs[t * 16 + l16][quad * 8];
      acc[t] = __builtin_amdgcn_mfma_f32_16x16x32_bf16(a, b, acc[t], 0, 0, 0);
    }
    __syncthreads();
  }
#pragma unroll
  for (int t = 0; t < 4; t++) {
#pragma unroll
    for (int r = 0; r < 4; r++) {
      int row = m0 + wave * 16 + quad * 4 + r;  // C/D: col=lane&15, row=quad*4+reg
      int col = n0 + t * 16 + l16;
      float v = acc[t][r];
      if (OUT_MODE == 0) {
        if (row < M && col < Nout)
          ((unsigned short*)Cp)[(size_t)row * Nout + col] = f2b(v);
      } else {  // ale layer-major
        if (row < M && col < 12)
          ((float*)Cp)[((size_t)(col >> 2) * EN + row) * 4 + (col & 3)] = v;
      }
    }
  }
  if constexpr (DO_ALD) {
    int h = (n0 * 4) / Nout;
#pragma unroll
    for (int r = 0; r < 4; r++) {
      float ps = 0.f, pd = 0.f;
#pragma unroll
      for (int t = 0; t < 4; t++) {
        int col = n0 + t * 16 + l16;
        float v = acc[t][r];
        ps += v * a_s[col];
        pd += v * a_d[col];
      }
#pragma unroll
      for (int off = 1; off < 16; off <<= 1) {
        ps += __shfl_xor(ps, off, 64);
        pd += __shfl_xor(pd, off, 64);
      }
      int row = m0 + wave * 16 + quad * 4 + r;
      if (l16 == 0 && row < M) {
        atomicAdd(&als[row * 4 + h], ps);
        atomicAdd(&ald[row * 4 + h], pd);
      }
    }
  }
}

// ---------------- self-loop al_e = mean of incoming al_e ----------------
// rowptr2 is [N*8+1]; node n's full range = [rowptr2[8n], rowptr2[8n+8]).
__global__ void k_loop_ale(const int* __restrict__ rowptr2, const int2* __restrict__ csr,
                           float* __restrict__ ale, int N, int E) {
  int n = blockIdx.x * 256 + threadIdx.x;
  if (n >= N) return;
  const size_t EN = (size_t)E + N;
  int s = rowptr2[(size_t)n * 8], e = rowptr2[(size_t)n * 8 + 8];
  float a[12];
#pragma unroll
  for (int j = 0; j < 12; j++) a[j] = 0.f;
  for (int p = s; p < e; p++) {
    int eid = csr[p].y;
#pragma unroll
    for (int L = 0; L < 3; L++) {
      float4 v = *(const float4*)(ale + (L * EN + eid) * 4);
      a[L * 4 + 0] += v.x; a[L * 4 + 1] += v.y;
      a[L * 4 + 2] += v.z; a[L * 4 + 3] += v.w;
    }
  }
  float inv = 1.0f / (float)((e - s) > 1 ? (e - s) : 1);
#pragma unroll
  for (int L = 0; L < 3; L++)
    *(float4*)(ale + (L * EN + E + n) * 4) =
        make_float4(a[L*4+0]*inv, a[L*4+1]*inv, a[L*4+2]*inv, a[L*4+3]*inv);
}

// ---------------- CSR online-softmax aggregation ----------------
// LPN lanes per node (8 for HC=256, 16 for HC=512), FPL=32 features/lane.
// csr is source-bucket-sorted per node: gathers walk src-space low->high,
// and co-resident blocks share an L2-resident moving window.
// rowptr2 indexing: node range = [rowptr2[8n], rowptr2[8n+8]).
// MODE 0: concat+bias+ReLU -> bf16. MODE 1: mean+bias -> f32.
template<int LPN, int MODE>
__global__ __launch_bounds__(256) void k_agg(const unsigned short* __restrict__ hs,
    const int* __restrict__ rowptr2, const int2* __restrict__ csr,
    const float* __restrict__ ale,  // layer base, [EN][4]
    const float* __restrict__ als, const float* __restrict__ ald,
    const float* __restrict__ bias, unsigned short* __restrict__ outb,
    float* __restrict__ outf, int N, int E) {
  const int FPL = 32;
  const int HC  = LPN * FPL;   // row width in shorts
  const int NG  = 64 / LPN;    // nodes per wave
  __shared__ float s_w[4][NG][LPN][4];
  __shared__ int   s_s[4][NG][LPN];
  const int wave = threadIdx.x >> 6;
  const int lane = threadIdx.x & 63;
  const int grp  = lane / LPN;
  const int sl   = lane % LPN;
  const int hd   = sl >> (LPN >> 3);  // head owning this lane's feature slice
  const int node = blockIdx.x * (4 * NG) + wave * NG + grp;
  if (node >= N) return;  // no __syncthreads in this kernel
  int start = rowptr2[(size_t)node * 8];
  int cnt   = rowptr2[(size_t)node * 8 + 8] - start;
  int total = cnt + 1;  // + self-loop
  const float4 aldv   = *(const float4*)(ald + (size_t)node * 4);
  const float4 selfev = *(const float4*)(ale + ((size_t)E + node) * 4);
  const float4 selfsv = *(const float4*)(als + (size_t)node * 4);
  // prefetch chunk 0's alpha inputs
  int    psidx = node;
  float4 pev = selfev, psv = selfsv;
  if (sl < cnt) {
    int2 se = csr[start + sl];
    psidx = se.x;
    pev = *(const float4*)(ale + (size_t)se.y * 4);
    psv = *(const float4*)(als + (size_t)se.x * 4);
  }
  float m0=-1e30f, m1=-1e30f, m2=-1e30f, m3=-1e30f;
  float d0=0.f, d1=0.f, d2=0.f, d3=0.f;
  float acc[FPL];
#pragma unroll
  for (int j = 0; j < FPL; j++) acc[j] = 0.f;
  for (int base = 0; base < total; base += LPN) {
    int ei = base + sl;
    bool active = ei < total;
    float a0=-1e30f, a1=-1e30f, a2=-1e30f, a3=-1e30f;
    int sidx = psidx;
    if (active) {
      a0 = psv.x + aldv.x + pev.x;
      a1 = psv.y + aldv.y + pev.y;
      a2 = psv.z + aldv.z + pev.z;
      a3 = psv.w + aldv.w + pev.w;
      a0 = a0 > 0.f ? a0 : 0.2f * a0;
      a1 = a1 > 0.f ? a1 : 0.2f * a1;
      a2 = a2 > 0.f ? a2 : 0.2f * a2;
      a3 = a3 > 0.f ? a3 : 0.2f * a3;
    }
    float c0=a0, c1=a1, c2=a2, c3=a3;
#pragma unroll
    for (int off = LPN / 2; off > 0; off >>= 1) {
      c0 = fmaxf(c0, __shfl_xor(c0, off, 64));
      c1 = fmaxf(c1, __shfl_xor(c1, off, 64));
      c2 = fmaxf(c2, __shfl_xor(c2, off, 64));
      c3 = fmaxf(c3, __shfl_xor(c3, off, 64));
    }
    float n0v = fmaxf(m0, c0), n1v = fmaxf(m1, c1), n2v = fmaxf(m2, c2), n3v = fmaxf(m3, c3);
    float p0 = active ? __expf(a0 - n0v) : 0.f;
    float p1 = active ? __expf(a1 - n1v) : 0.f;
    float p2 = active ? __expf(a2 - n2v) : 0.f;
    float p3 = active ? __expf(a3 - n3v) : 0.f;
    float s0=p0, s1=p1, s2=p2, s3=p3;
#pragma unroll
    for (int off = LPN / 2; off > 0; off >>= 1) {
      s0 += __shfl_xor(s0, off, 64);
      s1 += __shfl_xor(s1, off, 64);
      s2 += __shfl_xor(s2, off, 64);
      s3 += __shfl_xor(s3, off, 64);
    }
    float r0 = __expf(m0 - n0v), r1 = __expf(m1 - n1v);
    float r2 = __expf(m2 - n2v), r3 = __expf(m3 - n3v);
    d0 = d0 * r0 + s0; d1 = d1 * r1 + s1; d2 = d2 * r2 + s2; d3 = d3 * r3 + s3;
    float rh = hd == 0 ? r0 : hd == 1 ? r1 : hd == 2 ? r2 : r3;
#pragma unroll
    for (int j = 0; j < FPL; j++) acc[j] *= rh;
    m0 = n0v; m1 = n1v; m2 = n2v; m3 = n3v;
    *(float4*)&s_w[wave][grp][sl][0] = make_float4(p0, p1, p2, p3);
    s_s[wave][grp][sl] = sidx;
    __threadfence_block();  // per-wave LDS visibility
    // prefetch next chunk's alpha inputs (in flight during gather below)
    if (base + LPN < total) {
      int nei = base + LPN + sl;
      psidx = node; pev = selfev; psv = selfsv;
      if (nei < cnt) {
        int2 se = csr[start + nei];
        psidx = se.x;
        pev = *(const float4*)(ale + (size_t)se.y * 4);
        psv = *(const float4*)(als + (size_t)se.x * 4);
      }
    }
    int chunk = total - base; if (chunk > LPN) chunk = LPN;
    int t = 0;
    // 2 edges x 4 dwordx4 pinned in flight via asm operand list.
    for (; t + 2 <= chunk; t += 2) {
      float w0 = s_w[wave][grp][t][hd];
      float w1 = s_w[wave][grp][t + 1][hd];
      int   q0 = s_s[wave][grp][t];
      int   q1 = s_s[wave][grp][t + 1];
      const uintx4* p0p = (const uintx4*)(hs + (size_t)q0 * HC + sl * FPL);
      const uintx4* p1p = (const uintx4*)(hs + (size_t)q1 * HC + sl * FPL);
      uintx4 v0[4], v1[4];
#pragma unroll
      for (int q = 0; q < 4; q++) v0[q] = p0p[q];
#pragma unroll
      for (int q = 0; q < 4; q++) v1[q] = p1p[q];
      asm volatile("" :: "v"(v0[0]), "v"(v0[1]), "v"(v0[2]), "v"(v0[3]),
                         "v"(v1[0]), "v"(v1[1]), "v"(v1[2]), "v"(v1[3]));
#pragma unroll
      for (int q = 0; q < 4; q++) {
        uintx4 x = v0[q];
#pragma unroll
        for (int k = 0; k < 4; k++) {
          float lo = __uint_as_float(x[k] << 16);
          float hi = __uint_as_float(x[k] & 0xffff0000u);
          acc[q * 8 + k * 2 + 0] += w0 * lo;
          acc[q * 8 + k * 2 + 1] += w0 * hi;
        }
      }
#pragma unroll
      for (int q = 0; q < 4; q++) {
        uintx4 x = v1[q];
#pragma unroll
        for (int k = 0; k < 4; k++) {
          float lo = __uint_as_float(x[k] << 16);
          float hi = __uint_as_float(x[k] & 0xffff0000u);
          acc[q * 8 + k * 2 + 0] += w1 * lo;
          acc[q * 8 + k * 2 + 1] += w1 * hi;
        }
      }
    }
    if (t < chunk) {
      float w0 = s_w[wave][grp][t][hd];
      int   q0 = s_s[wave][grp][t];
      const uintx4* p0p = (const uintx4*)(hs + (size_t)q0 * HC + sl * FPL);
      uintx4 v0[4];
#pragma unroll
      for (int q = 0; q < 4; q++) v0[q] = p0p[q];
#pragma unroll
      for (int q = 0; q < 4; q++) {
        uintx4 x = v0[q];
#pragma unroll
        for (int k = 0; k < 4; k++) {
          float lo = __uint_as_float(x[k] << 16);
          float hi = __uint_as_float(x[k] & 0xffff0000u);
          acc[q * 8 + k * 2 + 0] += w0 * lo;
          acc[q * 8 + k * 2 + 1] += w0 * hi;
        }
      }
    }
  }
  float dh = hd == 0 ? d0 : hd == 1 ? d1 : hd == 2 ? d2 : d3;
  float inv = 1.0f / (dh + 1e-16f);
  if constexpr (MODE == 0) {
    unsigned short tmp[FPL];
#pragma unroll
    for (int j = 0; j < FPL; j++) {
      float v = acc[j] * inv + bias[sl * FPL + j];
      tmp[j] = f2b(fmaxf(v, 0.f));
    }
    unsigned short* op = outb + (size_t)node * HC + sl * FPL;
#pragma unroll
    for (int q = 0; q < 4; q++) ((uint4*)op)[q] = ((uint4*)tmp)[q];
  } else {
    // mean over heads (LPN=16): lane sl covers hs cols [sl*32, sl*32+32);
    // head=sl>>2, out col c = (sl&3)*32 + j. Sum lanes sl^4, sl^8.
#pragma unroll
    for (int j = 0; j < FPL; j++) {
      float v = acc[j] * inv;
      v += __shfl_xor(v, 4, 64);
      v += __shfl_xor(v, 8, 64);
      acc[j] = v * 0.25f;
    }
    if (sl < 4) {
      float* op = outf + (size_t)node * (4 * FPL) + sl * FPL;
#pragma unroll
      for (int j = 0; j < FPL; j++) op[j] = acc[j] + bias[sl * FPL + j];
    }
  }
}

// ---------------- pooling (batch is sorted) ----------------
__global__ __launch_bounds__(256) void k_pool(const float* __restrict__ out3,
    const int* __restrict__ bat, float* __restrict__ g, int* __restrict__ cntb, int N) {
  int wid = blockIdx.x * 4 + (threadIdx.x >> 6);
  int lane = threadIdx.x & 63;
  int per = (N + 255) / 256;
  int s = wid * per, e = s + per;
  if (e > N) e = N;
  if (s >= e) return;
  int cur = bat[s];
  float ax = 0.f, ay = 0.f; int run = 0;
  for (int n = s; n < e; n++) {
    int b = bat[n];
    if (b != cur) {
      atomicAdd(&g[cur * 128 + lane * 2], ax);
      atomicAdd(&g[cur * 128 + lane * 2 + 1], ay);
      if (lane == 0) atomicAdd(&cntb[cur], run);
      ax = 0.f; ay = 0.f; run = 0; cur = b;
    }
    float2 v = *(const float2*)(out3 + (size_t)n * 128 + lane * 2);
    ax += v.x; ay += v.y; run++;
  }
  atomicAdd(&g[cur * 128 + lane * 2], ax);
  atomicAdd(&g[cur * 128 + lane * 2 + 1], ay);
  if (lane == 0) atomicAdd(&cntb[cur], run);
}

// ---------------- final head ----------------
__global__ __launch_bounds__(320) void k_final(const float* __restrict__ g,
    const int* __restrict__ cntb, const float* __restrict__ Wa, const float* __restrict__ ba,
    const float* __restrict__ Wv, const float* __restrict__ bv, float* __restrict__ out) {
  __shared__ float gm[128];
  int b = blockIdx.x, t = threadIdx.x;
  if (t < 128) {
    float c = (float)cntb[b];
    gm[t] = g[b * 128 + t] / fmaxf(c, 1.f);
  }
  __syncthreads();
  if (t < 257) {
    float acc = 0.f;
    if (t < 256) {
      for (int k = 0; k < 128; k++) acc += gm[k] * Wa[k * 256 + t];
      acc += ba[t];
    } else {
      for (int k = 0; k < 128; k++) acc += gm[k] * Wv[k];
      acc += bv[0];
    }
    out[b * 257 + t] = acc;
  }
}

extern "C" void kernel_launch(void* const* d_in, const int* in_sizes, int n_in,
                              void* d_out, int out_size, void* d_ws, size_t ws_size,
                              hipStream_t stream) {
  const float* x   = (const float*)d_in[0];
  const int*   ei  = (const int*)  d_in[1];
  const float* ea  = (const float*)d_in[2];
  const int*   bat = (const int*)  d_in[3];
  const float* W1  = (const float*)d_in[4];
  const float* as1 = (const float*)d_in[5];
  const float* ad1 = (const float*)d_in[6];
  const float* We1 = (const float*)d_in[7];
  const float* ae1 = (const float*)d_in[8];
  const float* b1  = (const float*)d_in[9];
  const float* W2  = (const float*)d_in[10];
  const float* as2 = (const float*)d_in[11];
  const float* ad2 = (const float*)d_in[12];
  const float* We2 = (const float*)d_in[13];
  const float* ae2 = (const float*)d_in[14];
  const float* b2  = (const float*)d_in[15];
  const float* W3  = (const float*)d_in[16];
  const float* as3 = (const float*)d_in[17];
  const float* ad3 = (const float*)d_in[18];
  const float* We3 = (const float*)d_in[19];
  const float* ae3 = (const float*)d_in[20];
  const float* b3  = (const float*)d_in[21];
  const float* Wa  = (const float*)d_in[22];
  const float* ba  = (const float*)d_in[23];
  const float* Wv  = (const float*)d_in[24];
  const float* bv  = (const float*)d_in[25];
  (void)n_in; (void)out_size; (void)ws_size;

  const int N = in_sizes[0] / 192;  // 50000
  const int E = in_sizes[1] / 2;    // 800000
  const size_t EN = (size_t)E + N;
  const int* srcv = ei;
  const int* dstv = ei + E;
  const int N2 = N * 8;                      // bucketed rowptr length
  const int nbB = (N2 + 1023) / 1024;        // scan blocks over N2 (<=512)

  size_t off = 0;
  auto alloc = [&](size_t bytes) -> char* {
    char* p = (char*)d_ws + off;
    off += (bytes + 255) & ~(size_t)255;
    return p;
  };
  int* deg2    = (int*)alloc((size_t)N2 * 4);
  int* rowptr2 = (int*)alloc((size_t)(N2 + 1) * 4);
  int* cursor2 = (int*)alloc((size_t)N2 * 4);
  int* bsum    = (int*)alloc(512 * 4);
  int2* csr    = (int2*)alloc((size_t)E * 8);
  float* ale   = (float*)alloc(3 * EN * 4 * 4);  // [L][EN][4]
  unsigned short* Wept = (unsigned short*)alloc(16 * 64 * 2);
  unsigned short* W1t  = (unsigned short*)alloc(256 * 192 * 2);
  unsigned short* W2t  = (unsigned short*)alloc(256 * 256 * 2);
  unsigned short* W3t  = (unsigned short*)alloc(512 * 256 * 2);
  unsigned short* hs   = (unsigned short*)alloc((size_t)N * 512 * 2);
  unsigned short* h1   = (unsigned short*)alloc((size_t)N * 256 * 2);
  unsigned short* h2   = (unsigned short*)alloc((size_t)N * 256 * 2);
  float* out3  = (float*)alloc((size_t)N * 128 * 4);
  float* als_all = (float*)alloc((size_t)N * 4 * 4 * 6);  // als1,ald1,als2,ald2,als3,ald3
  float* g     = (float*)alloc(64 * 128 * 4 + 64 * 4);
  int* cntb    = (int*)(g + 64 * 128);
  float* als1 = als_all + (size_t)N * 4 * 0;
  float* ald1 = als_all + (size_t)N * 4 * 1;
  float* als2 = als_all + (size_t)N * 4 * 2;
  float* ald2 = als_all + (size_t)N * 4 * 3;
  float* als3 = als_all + (size_t)N * 4 * 4;
  float* ald3 = als_all + (size_t)N * 4 * 5;

  hipMemsetAsync(deg2, 0, (size_t)N2 * 4, stream);
  hipMemsetAsync(als_all, 0, (size_t)N * 4 * 4 * 6, stream);
  hipMemsetAsync(g, 0, 64 * 128 * 4 + 64 * 4, stream);

  k_deg2<<<(E + 255) / 256, 256, 0, stream>>>(srcv, dstv, deg2, E);
  k_scan1<<<nbB, 256, 0, stream>>>(deg2, rowptr2, bsum, N2);
  k_scan2<<<1, 512, 0, stream>>>(bsum, nbB);
  k_scan3<<<nbB, 256, 0, stream>>>(rowptr2, cursor2, bsum, N2, E);
  k_scatter<<<(E + 255) / 256, 256, 0, stream>>>(srcv, dstv, cursor2, csr, E);
  k_wt<<<(192 * 256 + 255) / 256, 256, 0, stream>>>(W1, W1t, 192, 256);
  k_wt<<<(256 * 256 + 255) / 256, 256, 0, stream>>>(W2, W2t, 256, 256);
  k_wt<<<(256 * 512 + 255) / 256, 256, 0, stream>>>(W3, W3t, 256, 512);
  k_wep<<<3, 256, 0, stream>>>(We1, ae1, We2, ae2, We3, ae3, Wept);
  // al_e for all 3 layers in one GEMM over edge_attr (layer-major output)
  k_gemm<true, 2, false><<<dim3((E + 63) / 64, 1), 256, 0, stream>>>(
      ea, Wept, ale, E, 16, 64, (int)EN, nullptr, nullptr, nullptr, nullptr);
  k_loop_ale<<<(N + 255) / 256, 256, 0, stream>>>(rowptr2, csr, ale, N, E);
  // layer 1
  k_gemm<true, 0, true><<<dim3((N + 63) / 64, 4), 256, 0, stream>>>(
      x, W1t, hs, N, 256, 192, 0, as1, ad1, als1, ald1);
  k_agg<8, 0><<<(N + 31) / 32, 256, 0, stream>>>(
      hs, rowptr2, csr, ale + 0 * EN * 4, als1, ald1, b1, h1, nullptr, N, E);
  // layer 2
  k_gemm<false, 0, true><<<dim3((N + 63) / 64, 4), 256, 0, stream>>>(
      h1, W2t, hs, N, 256, 256, 0, as2, ad2, als2, ald2);
  k_agg<8, 0><<<(N + 31) / 32, 256, 0, stream>>>(
      hs, rowptr2, csr, ale + 1 * EN * 4, als2, ald2, b2, h2, nullptr, N, E);
  // layer 3
  k_gemm<false, 0, true><<<dim3((N + 63) / 64, 8), 256, 0, stream>>>(
      h2, W3t, hs, N, 512, 256, 0, as3, ad3, als3, ald3);
  k_agg<16, 1><<<(N + 15) / 16, 256, 0, stream>>>(
      hs, rowptr2, csr, ale + 2 * EN * 4, als3, ald3, b3, nullptr, out3, N, E);
  // pool + head
  k_pool<<<64, 256, 0, stream>>>(out3, bat, g, cntb, N);
  k_final<<<64, 320, 0, stream>>>(g, cntb, Wa, ba, Wv, bv, (float*)d_out);
}

// Round 8
// 1014.505 us; speedup vs baseline: 1.0526x; 1.0524x over previous
//
#include <hip/hip_runtime.h>
#include <hip/hip_bf16.h>

// GAT 3-layer + pool + dense head for MI355X (gfx950).
// R2: k_agg 16-lanes-per-node; k_ald folded into GEMM; ale layer-major.
// R3-R9: MLP/geometry/bucket-sort probes all NULL. Surviving invariant:
// ~5.9G random row-gathers/s regardless of row size (512B->3.5TB/s,
// 1024B->6.2TB/s) => DRAM activation-rate cap (~10G act/s; HBM page ~1KB).
// FETCH accounting: 472MB = 435 hs + ~36 ale-miss => per-edge activations
// = 1.0 (hs row) + ~0.7 (random 16B ale by ORIGINAL edge id).
// R10: position-indexed ale. The ale GEMM gathers A rows via csr[pos].y
// (random 256B ea reads, once, inside a throughput kernel) and writes
// ale[L][pos] sequentially; k_agg and k_loop_ale now read ale sequentially.
// Per-edge random activations in each agg: 1.7 -> 1.0.

typedef __attribute__((ext_vector_type(8))) short short8;
typedef __attribute__((ext_vector_type(4))) float floatx4;
typedef __attribute__((ext_vector_type(4))) unsigned int uintx4;

#define DEV __device__ __forceinline__

DEV unsigned short f2b(float f) {
  union { float f; unsigned u; } v; v.f = f;
  unsigned r = v.u + 0x7FFFu + ((v.u >> 16) & 1u);  // RNE
  return (unsigned short)(r >> 16);
}
DEV float b2f(unsigned short u) {
  union { unsigned u; float f; } v; v.u = ((unsigned)u) << 16;
  return v.f;
}

// ---------------- bucketed CSR build ----------------
// deg2[n*8 + b] = #edges into n with src in bucket b (b = src>>13, 0..6).
__global__ void k_deg2(const int* __restrict__ src, const int* __restrict__ dst,
                       int* __restrict__ deg2, int E) {
  int e = blockIdx.x * 256 + threadIdx.x;
  if (e < E) atomicAdd(&deg2[(size_t)dst[e] * 8 + (src[e] >> 13)], 1);
}

// block-local exclusive scan over 1024 elems (256 thr x 4)
__global__ __launch_bounds__(256) void k_scan1(const int* __restrict__ deg,
    int* __restrict__ rowptr, int* __restrict__ bsum, int N) {
  __shared__ int sd[256];
  int b = blockIdx.x, tid = threadIdx.x;
  int i0 = b * 1024 + tid * 4;
  int v[4]; int s = 0;
#pragma unroll
  for (int j = 0; j < 4; j++) { int i = i0 + j; v[j] = (i < N) ? deg[i] : 0; s += v[j]; }
  sd[tid] = s;
  __syncthreads();
  for (int off = 1; off < 256; off <<= 1) {
    int t = (tid >= off) ? sd[tid - off] : 0;
    __syncthreads();
    sd[tid] += t;
    __syncthreads();
  }
  int run = sd[tid] - s;  // exclusive
#pragma unroll
  for (int j = 0; j < 4; j++) { int i = i0 + j; if (i < N) rowptr[i] = run; run += v[j]; }
  if (tid == 255) bsum[b] = sd[255];
}

// scan over up to 512 block sums
__global__ __launch_bounds__(512) void k_scan2(int* __restrict__ bsum, int nb) {
  __shared__ int sd[512];
  int tid = threadIdx.x;
  int v = (tid < nb) ? bsum[tid] : 0;
  sd[tid] = v;
  __syncthreads();
  for (int off = 1; off < 512; off <<= 1) {
    int t = (tid >= off) ? sd[tid - off] : 0;
    __syncthreads();
    sd[tid] += t;
    __syncthreads();
  }
  if (tid < nb) bsum[tid] = sd[tid] - v;  // exclusive
}

__global__ __launch_bounds__(256) void k_scan3(int* __restrict__ rowptr,
    int* __restrict__ cursor, const int* __restrict__ bsum, int N, int E) {
  int b = blockIdx.x, tid = threadIdx.x;
  int add = bsum[b];
  int i0 = b * 1024 + tid * 4;
#pragma unroll
  for (int j = 0; j < 4; j++) {
    int i = i0 + j;
    if (i < N) { int r = rowptr[i] + add; rowptr[i] = r; cursor[i] = r; }
  }
  if (b == 0 && tid == 0) rowptr[N] = E;
}

__global__ void k_scatter(const int* __restrict__ src, const int* __restrict__ dst,
    int* __restrict__ cursor, int2* __restrict__ csr, int E) {
  int e = blockIdx.x * 256 + threadIdx.x;
  if (e < E) {
    int s = src[e], d = dst[e];
    int pos = atomicAdd(&cursor[(size_t)d * 8 + (s >> 13)], 1);
    csr[pos] = make_int2(s, e);
  }
}

// ---------------- weight prep ----------------
__global__ void k_wt(const float* __restrict__ W, unsigned short* __restrict__ Wt,
                     int K, int Nout) {
  int idx = blockIdx.x * 256 + threadIdx.x;
  if (idx < K * Nout) {
    int n = idx / K, k = idx - n * K;
    Wt[idx] = f2b(W[(size_t)k * Nout + n]);
  }
}

// Wept[j][c], j = L*4+h (12 rows used, 16 total)
__global__ void k_wep(const float* __restrict__ We1, const float* __restrict__ ae1,
                      const float* __restrict__ We2, const float* __restrict__ ae2,
                      const float* __restrict__ We3, const float* __restrict__ ae3,
                      unsigned short* __restrict__ Wept) {
  int t = blockIdx.x * 256 + threadIdx.x;  // 0..767
  int j = t >> 6, c = t & 63;
  int L = j >> 2, h = j & 3;
  const float* We = (L == 0) ? We1 : (L == 1) ? We2 : We3;
  const float* ae = (L == 0) ? ae1 : (L == 1) ? ae2 : ae3;
  int C = (L == 2) ? 128 : 64;
  int HC = 4 * C;
  float s = 0.f;
  for (int cc = 0; cc < C; cc++) s += We[(size_t)c * HC + h * C + cc] * ae[h * C + cc];
  Wept[j * 64 + c] = f2b(s);
  if (t < 256) {
    int jj = 12 + (t >> 6);
    Wept[jj * 64 + (t & 63)] = 0;
  }
}

// ---------------- GEMM: C[M,Nout] = A[M,K] @ Bt[Nout,K]^T ----------------
// OUT_MODE: 0 = bf16 C; 2 = ale position-major f32 ([L][EN][4], col=L*4+h,
//   col<12, A row gm gathered via eidmap[gm].y so output row = csr position)
// DO_ALD: epilogue also accumulates als/ald (head = n0*4/Nout, uniform per block)
template<bool A_F32, int OUT_MODE, bool DO_ALD>
__global__ __launch_bounds__(256) void k_gemm(const void* __restrict__ Ap,
    const unsigned short* __restrict__ Bt, void* __restrict__ Cp,
    int M, int Nout, int K, int EN,
    const float* __restrict__ a_s, const float* __restrict__ a_d,
    float* __restrict__ als, float* __restrict__ ald,
    const int2* __restrict__ eidmap) {
  __shared__ unsigned short As[64][40];
  __shared__ unsigned short Bs[64][40];
  const int tid = threadIdx.x;
  const int wave = tid >> 6, lane = tid & 63;
  const int quad = lane >> 4, l16 = lane & 15;
  const int m0 = blockIdx.x * 64, n0 = blockIdx.y * 64;
  const int arow = tid >> 2, acg = (tid & 3) * 8;
  floatx4 acc[4] = {{0,0,0,0},{0,0,0,0},{0,0,0,0},{0,0,0,0}};
  for (int k0 = 0; k0 < K; k0 += 32) {
    {
      int gm = m0 + arow;
      unsigned short tmp[8];
      if (A_F32) {
        const float* Af = (const float*)Ap;
        if (gm < M) {
          size_t ar = (size_t)gm;
          if (OUT_MODE == 2) ar = (size_t)eidmap[gm].y;
          const float4* p = (const float4*)(Af + ar * K + k0 + acg);
          float4 u0 = p[0], u1 = p[1];
          tmp[0]=f2b(u0.x); tmp[1]=f2b(u0.y); tmp[2]=f2b(u0.z); tmp[3]=f2b(u0.w);
          tmp[4]=f2b(u1.x); tmp[5]=f2b(u1.y); tmp[6]=f2b(u1.z); tmp[7]=f2b(u1.w);
        } else {
#pragma unroll
          for (int j = 0; j < 8; j++) tmp[j] = 0;
        }
      } else {
        const unsigned short* Ab = (const unsigned short*)Ap;
        uint4 u = {0,0,0,0};
        if (gm < M) u = *(const uint4*)(Ab + (size_t)gm * K + k0 + acg);
        *(uint4*)tmp = u;
      }
      *(uint4*)&As[arow][acg] = *(uint4*)tmp;
      int gn = n0 + arow;
      uint4 bv = {0,0,0,0};
      if (gn < Nout) bv = *(const uint4*)(Bt + (size_t)gn * K + k0 + acg);
      *(uint4*)&Bs[arow][acg] = bv;
    }
    __syncthreads();
    short8 a = *(const short8*)&As[wave * 16 + l16][quad * 8];
#pragma unroll
    for (int t = 0; t < 4; t++) {
      short8 b = *(const short8*)&Bs[t * 16 + l16][quad * 8];
      acc[t] = __builtin_amdgcn_mfma_f32_16x16x32_bf16(a, b, acc[t], 0, 0, 0);
    }
    __syncthreads();
  }
#pragma unroll
  for (int t = 0; t < 4; t++) {
#pragma unroll
    for (int r = 0; r < 4; r++) {
      int row = m0 + wave * 16 + quad * 4 + r;  // C/D: col=lane&15, row=quad*4+reg
      int col = n0 + t * 16 + l16;
      float v = acc[t][r];
      if (OUT_MODE == 0) {
        if (row < M && col < Nout)
          ((unsigned short*)Cp)[(size_t)row * Nout + col] = f2b(v);
      } else {  // ale position-major
        if (row < M && col < 12)
          ((float*)Cp)[((size_t)(col >> 2) * EN + row) * 4 + (col & 3)] = v;
      }
    }
  }
  if constexpr (DO_ALD) {
    int h = (n0 * 4) / Nout;
#pragma unroll
    for (int r = 0; r < 4; r++) {
      float ps = 0.f, pd = 0.f;
#pragma unroll
      for (int t = 0; t < 4; t++) {
        int col = n0 + t * 16 + l16;
        float v = acc[t][r];
        ps += v * a_s[col];
        pd += v * a_d[col];
      }
#pragma unroll
      for (int off = 1; off < 16; off <<= 1) {
        ps += __shfl_xor(ps, off, 64);
        pd += __shfl_xor(pd, off, 64);
      }
      int row = m0 + wave * 16 + quad * 4 + r;
      if (l16 == 0 && row < M) {
        atomicAdd(&als[row * 4 + h], ps);
        atomicAdd(&ald[row * 4 + h], pd);
      }
    }
  }
}

// ---------------- self-loop al_e = mean of incoming al_e ----------------
// rowptr2 is [N*8+1]; node n's range = [rowptr2[8n], rowptr2[8n+8]).
// ale is position-indexed: contiguous read per node.
__global__ void k_loop_ale(const int* __restrict__ rowptr2,
                           float* __restrict__ ale, int N, int E) {
  int n = blockIdx.x * 256 + threadIdx.x;
  if (n >= N) return;
  const size_t EN = (size_t)E + N;
  int s = rowptr2[(size_t)n * 8], e = rowptr2[(size_t)n * 8 + 8];
  float a[12];
#pragma unroll
  for (int j = 0; j < 12; j++) a[j] = 0.f;
  for (int p = s; p < e; p++) {
#pragma unroll
    for (int L = 0; L < 3; L++) {
      float4 v = *(const float4*)(ale + (L * EN + p) * 4);
      a[L * 4 + 0] += v.x; a[L * 4 + 1] += v.y;
      a[L * 4 + 2] += v.z; a[L * 4 + 3] += v.w;
    }
  }
  float inv = 1.0f / (float)((e - s) > 1 ? (e - s) : 1);
#pragma unroll
  for (int L = 0; L < 3; L++)
    *(float4*)(ale + (L * EN + E + n) * 4) =
        make_float4(a[L*4+0]*inv, a[L*4+1]*inv, a[L*4+2]*inv, a[L*4+3]*inv);
}

// ---------------- CSR online-softmax aggregation ----------------
// LPN lanes per node (8 for HC=256, 16 for HC=512), FPL=32 features/lane.
// ale is position-indexed => alpha-phase reads are csr(seq) + ale(seq) +
// als(L2-resident); the only random stream left is the hs row gather.
// rowptr2 indexing: node range = [rowptr2[8n], rowptr2[8n+8]).
// MODE 0: concat+bias+ReLU -> bf16. MODE 1: mean+bias -> f32.
template<int LPN, int MODE>
__global__ __launch_bounds__(256) void k_agg(const unsigned short* __restrict__ hs,
    const int* __restrict__ rowptr2, const int2* __restrict__ csr,
    const float* __restrict__ ale,  // layer base, [EN][4], position-indexed
    const float* __restrict__ als, const float* __restrict__ ald,
    const float* __restrict__ bias, unsigned short* __restrict__ outb,
    float* __restrict__ outf, int N, int E) {
  const int FPL = 32;
  const int HC  = LPN * FPL;   // row width in shorts
  const int NG  = 64 / LPN;    // nodes per wave
  __shared__ float s_w[4][NG][LPN][4];
  __shared__ int   s_s[4][NG][LPN];
  const int wave = threadIdx.x >> 6;
  const int lane = threadIdx.x & 63;
  const int grp  = lane / LPN;
  const int sl   = lane % LPN;
  const int hd   = sl >> (LPN >> 3);  // head owning this lane's feature slice
  const int node = blockIdx.x * (4 * NG) + wave * NG + grp;
  if (node >= N) return;  // no __syncthreads in this kernel
  int start = rowptr2[(size_t)node * 8];
  int cnt   = rowptr2[(size_t)node * 8 + 8] - start;
  int total = cnt + 1;  // + self-loop
  const float4 aldv   = *(const float4*)(ald + (size_t)node * 4);
  const float4 selfev = *(const float4*)(ale + ((size_t)E + node) * 4);
  const float4 selfsv = *(const float4*)(als + (size_t)node * 4);
  // prefetch chunk 0's alpha inputs
  int    psidx = node;
  float4 pev = selfev, psv = selfsv;
  if (sl < cnt) {
    int2 se = csr[start + sl];
    psidx = se.x;
    pev = *(const float4*)(ale + (size_t)(start + sl) * 4);
    psv = *(const float4*)(als + (size_t)se.x * 4);
  }
  float m0=-1e30f, m1=-1e30f, m2=-1e30f, m3=-1e30f;
  float d0=0.f, d1=0.f, d2=0.f, d3=0.f;
  float acc[FPL];
#pragma unroll
  for (int j = 0; j < FPL; j++) acc[j] = 0.f;
  for (int base = 0; base < total; base += LPN) {
    int ei = base + sl;
    bool active = ei < total;
    float a0=-1e30f, a1=-1e30f, a2=-1e30f, a3=-1e30f;
    int sidx = psidx;
    if (active) {
      a0 = psv.x + aldv.x + pev.x;
      a1 = psv.y + aldv.y + pev.y;
      a2 = psv.z + aldv.z + pev.z;
      a3 = psv.w + aldv.w + pev.w;
      a0 = a0 > 0.f ? a0 : 0.2f * a0;
      a1 = a1 > 0.f ? a1 : 0.2f * a1;
      a2 = a2 > 0.f ? a2 : 0.2f * a2;
      a3 = a3 > 0.f ? a3 : 0.2f * a3;
    }
    float c0=a0, c1=a1, c2=a2, c3=a3;
#pragma unroll
    for (int off = LPN / 2; off > 0; off >>= 1) {
      c0 = fmaxf(c0, __shfl_xor(c0, off, 64));
      c1 = fmaxf(c1, __shfl_xor(c1, off, 64));
      c2 = fmaxf(c2, __shfl_xor(c2, off, 64));
      c3 = fmaxf(c3, __shfl_xor(c3, off, 64));
    }
    float n0v = fmaxf(m0, c0), n1v = fmaxf(m1, c1), n2v = fmaxf(m2, c2), n3v = fmaxf(m3, c3);
    float p0 = active ? __expf(a0 - n0v) : 0.f;
    float p1 = active ? __expf(a1 - n1v) : 0.f;
    float p2 = active ? __expf(a2 - n2v) : 0.f;
    float p3 = active ? __expf(a3 - n3v) : 0.f;
    float s0=p0, s1=p1, s2=p2, s3=p3;
#pragma unroll
    for (int off = LPN / 2; off > 0; off >>= 1) {
      s0 += __shfl_xor(s0, off, 64);
      s1 += __shfl_xor(s1, off, 64);
      s2 += __shfl_xor(s2, off, 64);
      s3 += __shfl_xor(s3, off, 64);
    }
    float r0 = __expf(m0 - n0v), r1 = __expf(m1 - n1v);
    float r2 = __expf(m2 - n2v), r3 = __expf(m3 - n3v);
    d0 = d0 * r0 + s0; d1 = d1 * r1 + s1; d2 = d2 * r2 + s2; d3 = d3 * r3 + s3;
    float rh = hd == 0 ? r0 : hd == 1 ? r1 : hd == 2 ? r2 : r3;
#pragma unroll
    for (int j = 0; j < FPL; j++) acc[j] *= rh;
    m0 = n0v; m1 = n1v; m2 = n2v; m3 = n3v;
    *(float4*)&s_w[wave][grp][sl][0] = make_float4(p0, p1, p2, p3);
    s_s[wave][grp][sl] = sidx;
    __threadfence_block();  // per-wave LDS visibility
    // prefetch next chunk's alpha inputs (in flight during gather below)
    if (base + LPN < total) {
      int nei = base + LPN + sl;
      psidx = node; pev = selfev; psv = selfsv;
      if (nei < cnt) {
        int2 se = csr[start + nei];
        psidx = se.x;
        pev = *(const float4*)(ale + (size_t)(start + nei) * 4);
        psv = *(const float4*)(als + (size_t)se.x * 4);
      }
    }
    int chunk = total - base; if (chunk > LPN) chunk = LPN;
    int t = 0;
    // 2 edges x 4 dwordx4 pinned in flight via asm operand list.
    for (; t + 2 <= chunk; t += 2) {
      float w0 = s_w[wave][grp][t][hd];
      float w1 = s_w[wave][grp][t + 1][hd];
      int   q0 = s_s[wave][grp][t];
      int   q1 = s_s[wave][grp][t + 1];
      const uintx4* p0p = (const uintx4*)(hs + (size_t)q0 * HC + sl * FPL);
      const uintx4* p1p = (const uintx4*)(hs + (size_t)q1 * HC + sl * FPL);
      uintx4 v0[4], v1[4];
#pragma unroll
      for (int q = 0; q < 4; q++) v0[q] = p0p[q];
#pragma unroll
      for (int q = 0; q < 4; q++) v1[q] = p1p[q];
      asm volatile("" :: "v"(v0[0]), "v"(v0[1]), "v"(v0[2]), "v"(v0[3]),
                         "v"(v1[0]), "v"(v1[1]), "v"(v1[2]), "v"(v1[3]));
#pragma unroll
      for (int q = 0; q < 4; q++) {
        uintx4 x = v0[q];
#pragma unroll
        for (int k = 0; k < 4; k++) {
          float lo = __uint_as_float(x[k] << 16);
          float hi = __uint_as_float(x[k] & 0xffff0000u);
          acc[q * 8 + k * 2 + 0] += w0 * lo;
          acc[q * 8 + k * 2 + 1] += w0 * hi;
        }
      }
#pragma unroll
      for (int q = 0; q < 4; q++) {
        uintx4 x = v1[q];
#pragma unroll
        for (int k = 0; k < 4; k++) {
          float lo = __uint_as_float(x[k] << 16);
          float hi = __uint_as_float(x[k] & 0xffff0000u);
          acc[q * 8 + k * 2 + 0] += w1 * lo;
          acc[q * 8 + k * 2 + 1] += w1 * hi;
        }
      }
    }
    if (t < chunk) {
      float w0 = s_w[wave][grp][t][hd];
      int   q0 = s_s[wave][grp][t];
      const uintx4* p0p = (const uintx4*)(hs + (size_t)q0 * HC + sl * FPL);
      uintx4 v0[4];
#pragma unroll
      for (int q = 0; q < 4; q++) v0[q] = p0p[q];
#pragma unroll
      for (int q = 0; q < 4; q++) {
        uintx4 x = v0[q];
#pragma unroll
        for (int k = 0; k < 4; k++) {
          float lo = __uint_as_float(x[k] << 16);
          float hi = __uint_as_float(x[k] & 0xffff0000u);
          acc[q * 8 + k * 2 + 0] += w0 * lo;
          acc[q * 8 + k * 2 + 1] += w0 * hi;
        }
      }
    }
  }
  float dh = hd == 0 ? d0 : hd == 1 ? d1 : hd == 2 ? d2 : d3;
  float inv = 1.0f / (dh + 1e-16f);
  if constexpr (MODE == 0) {
    unsigned short tmp[FPL];
#pragma unroll
    for (int j = 0; j < FPL; j++) {
      float v = acc[j] * inv + bias[sl * FPL + j];
      tmp[j] = f2b(fmaxf(v, 0.f));
    }
    unsigned short* op = outb + (size_t)node * HC + sl * FPL;
#pragma unroll
    for (int q = 0; q < 4; q++) ((uint4*)op)[q] = ((uint4*)tmp)[q];
  } else {
    // mean over heads (LPN=16): lane sl covers hs cols [sl*32, sl*32+32);
    // head=sl>>2, out col c = (sl&3)*32 + j. Sum lanes sl^4, sl^8.
#pragma unroll
    for (int j = 0; j < FPL; j++) {
      float v = acc[j] * inv;
      v += __shfl_xor(v, 4, 64);
      v += __shfl_xor(v, 8, 64);
      acc[j] = v * 0.25f;
    }
    if (sl < 4) {
      float* op = outf + (size_t)node * (4 * FPL) + sl * FPL;
#pragma unroll
      for (int j = 0; j < FPL; j++) op[j] = acc[j] + bias[sl * FPL + j];
    }
  }
}

// ---------------- pooling (batch is sorted) ----------------
__global__ __launch_bounds__(256) void k_pool(const float* __restrict__ out3,
    const int* __restrict__ bat, float* __restrict__ g, int* __restrict__ cntb, int N) {
  int wid = blockIdx.x * 4 + (threadIdx.x >> 6);
  int lane = threadIdx.x & 63;
  int per = (N + 255) / 256;
  int s = wid * per, e = s + per;
  if (e > N) e = N;
  if (s >= e) return;
  int cur = bat[s];
  float ax = 0.f, ay = 0.f; int run = 0;
  for (int n = s; n < e; n++) {
    int b = bat[n];
    if (b != cur) {
      atomicAdd(&g[cur * 128 + lane * 2], ax);
      atomicAdd(&g[cur * 128 + lane * 2 + 1], ay);
      if (lane == 0) atomicAdd(&cntb[cur], run);
      ax = 0.f; ay = 0.f; run = 0; cur = b;
    }
    float2 v = *(const float2*)(out3 + (size_t)n * 128 + lane * 2);
    ax += v.x; ay += v.y; run++;
  }
  atomicAdd(&g[cur * 128 + lane * 2], ax);
  atomicAdd(&g[cur * 128 + lane * 2 + 1], ay);
  if (lane == 0) atomicAdd(&cntb[cur], run);
}

// ---------------- final head ----------------
__global__ __launch_bounds__(320) void k_final(const float* __restrict__ g,
    const int* __restrict__ cntb, const float* __restrict__ Wa, const float* __restrict__ ba,
    const float* __restrict__ Wv, const float* __restrict__ bv, float* __restrict__ out) {
  __shared__ float gm[128];
  int b = blockIdx.x, t = threadIdx.x;
  if (t < 128) {
    float c = (float)cntb[b];
    gm[t] = g[b * 128 + t] / fmaxf(c, 1.f);
  }
  __syncthreads();
  if (t < 257) {
    float acc = 0.f;
    if (t < 256) {
      for (int k = 0; k < 128; k++) acc += gm[k] * Wa[k * 256 + t];
      acc += ba[t];
    } else {
      for (int k = 0; k < 128; k++) acc += gm[k] * Wv[k];
      acc += bv[0];
    }
    out[b * 257 + t] = acc;
  }
}

extern "C" void kernel_launch(void* const* d_in, const int* in_sizes, int n_in,
                              void* d_out, int out_size, void* d_ws, size_t ws_size,
                              hipStream_t stream) {
  const float* x   = (const float*)d_in[0];
  const int*   ei  = (const int*)  d_in[1];
  const float* ea  = (const float*)d_in[2];
  const int*   bat = (const int*)  d_in[3];
  const float* W1  = (const float*)d_in[4];
  const float* as1 = (const float*)d_in[5];
  const float* ad1 = (const float*)d_in[6];
  const float* We1 = (const float*)d_in[7];
  const float* ae1 = (const float*)d_in[8];
  const float* b1  = (const float*)d_in[9];
  const float* W2  = (const float*)d_in[10];
  const float* as2 = (const float*)d_in[11];
  const float* ad2 = (const float*)d_in[12];
  const float* We2 = (const float*)d_in[13];
  const float* ae2 = (const float*)d_in[14];
  const float* b2  = (const float*)d_in[15];
  const float* W3  = (const float*)d_in[16];
  const float* as3 = (const float*)d_in[17];
  const float* ad3 = (const float*)d_in[18];
  const float* We3 = (const float*)d_in[19];
  const float* ae3 = (const float*)d_in[20];
  const float* b3  = (const float*)d_in[21];
  const float* Wa  = (const float*)d_in[22];
  const float* ba  = (const float*)d_in[23];
  const float* Wv  = (const float*)d_in[24];
  const float* bv  = (const float*)d_in[25];
  (void)n_in; (void)out_size; (void)ws_size;

  const int N = in_sizes[0] / 192;  // 50000
  const int E = in_sizes[1] / 2;    // 800000
  const size_t EN = (size_t)E + N;
  const int* srcv = ei;
  const int* dstv = ei + E;
  const int N2 = N * 8;                      // bucketed rowptr length
  const int nbB = (N2 + 1023) / 1024;        // scan blocks over N2 (<=512)

  size_t off = 0;
  auto alloc = [&](size_t bytes) -> char* {
    char* p = (char*)d_ws + off;
    off += (bytes + 255) & ~(size_t)255;
    return p;
  };
  int* deg2    = (int*)alloc((size_t)N2 * 4);
  int* rowptr2 = (int*)alloc((size_t)(N2 + 1) * 4);
  int* cursor2 = (int*)alloc((size_t)N2 * 4);
  int* bsum    = (int*)alloc(512 * 4);
  int2* csr    = (int2*)alloc((size_t)E * 8);
  float* ale   = (float*)alloc(3 * EN * 4 * 4);  // [L][EN][4], position-indexed
  unsigned short* Wept = (unsigned short*)alloc(16 * 64 * 2);
  unsigned short* W1t  = (unsigned short*)alloc(256 * 192 * 2);
  unsigned short* W2t  = (unsigned short*)alloc(256 * 256 * 2);
  unsigned short* W3t  = (unsigned short*)alloc(512 * 256 * 2);
  unsigned short* hs   = (unsigned short*)alloc((size_t)N * 512 * 2);
  unsigned short* h1   = (unsigned short*)alloc((size_t)N * 256 * 2);
  unsigned short* h2   = (unsigned short*)alloc((size_t)N * 256 * 2);
  float* out3  = (float*)alloc((size_t)N * 128 * 4);
  float* als_all = (float*)alloc((size_t)N * 4 * 4 * 6);  // als1,ald1,als2,ald2,als3,ald3
  float* g     = (float*)alloc(64 * 128 * 4 + 64 * 4);
  int* cntb    = (int*)(g + 64 * 128);
  float* als1 = als_all + (size_t)N * 4 * 0;
  float* ald1 = als_all + (size_t)N * 4 * 1;
  float* als2 = als_all + (size_t)N * 4 * 2;
  float* ald2 = als_all + (size_t)N * 4 * 3;
  float* als3 = als_all + (size_t)N * 4 * 4;
  float* ald3 = als_all + (size_t)N * 4 * 5;

  hipMemsetAsync(deg2, 0, (size_t)N2 * 4, stream);
  hipMemsetAsync(als_all, 0, (size_t)N * 4 * 4 * 6, stream);
  hipMemsetAsync(g, 0, 64 * 128 * 4 + 64 * 4, stream);

  k_deg2<<<(E + 255) / 256, 256, 0, stream>>>(srcv, dstv, deg2, E);
  k_scan1<<<nbB, 256, 0, stream>>>(deg2, rowptr2, bsum, N2);
  k_scan2<<<1, 512, 0, stream>>>(bsum, nbB);
  k_scan3<<<nbB, 256, 0, stream>>>(rowptr2, cursor2, bsum, N2, E);
  k_scatter<<<(E + 255) / 256, 256, 0, stream>>>(srcv, dstv, cursor2, csr, E);
  k_wt<<<(192 * 256 + 255) / 256, 256, 0, stream>>>(W1, W1t, 192, 256);
  k_wt<<<(256 * 256 + 255) / 256, 256, 0, stream>>>(W2, W2t, 256, 256);
  k_wt<<<(256 * 512 + 255) / 256, 256, 0, stream>>>(W3, W3t, 256, 512);
  k_wep<<<3, 256, 0, stream>>>(We1, ae1, We2, ae2, We3, ae3, Wept);
  // al_e for all 3 layers in one GEMM over edge_attr, A gathered via csr[pos].y
  // so the output is position-indexed (sequential for all later readers).
  k_gemm<true, 2, false><<<dim3((E + 63) / 64, 1), 256, 0, stream>>>(
      ea, Wept, ale, E, 16, 64, (int)EN, nullptr, nullptr, nullptr, nullptr, csr);
  k_loop_ale<<<(N + 255) / 256, 256, 0, stream>>>(rowptr2, ale, N, E);
  // layer 1
  k_gemm<true, 0, true><<<dim3((N + 63) / 64, 4), 256, 0, stream>>>(
      x, W1t, hs, N, 256, 192, 0, as1, ad1, als1, ald1, nullptr);
  k_agg<8, 0><<<(N + 31) / 32, 256, 0, stream>>>(
      hs, rowptr2, csr, ale + 0 * EN * 4, als1, ald1, b1, h1, nullptr, N, E);
  // layer 2
  k_gemm<false, 0, true><<<dim3((N + 63) / 64, 4), 256, 0, stream>>>(
      h1, W2t, hs, N, 256, 256, 0, as2, ad2, als2, ald2, nullptr);
  k_agg<8, 0><<<(N + 31) / 32, 256, 0, stream>>>(
      hs, rowptr2, csr, ale + 1 * EN * 4, als2, ald2, b2, h2, nullptr, N, E);
  // layer 3
  k_gemm<false, 0, true><<<dim3((N + 63) / 64, 8), 256, 0, stream>>>(
      h2, W3t, hs, N, 512, 256, 0, as3, ad3, als3, ald3, nullptr);
  k_agg<16, 1><<<(N + 15) / 16, 256, 0, stream>>>(
      hs, rowptr2, csr, ale + 2 * EN * 4, als3, ald3, b3, nullptr, out3, N, E);
  // pool + head
  k_pool<<<64, 256, 0, stream>>>(out3, bat, g, cntb, N);
  k_final<<<64, 320, 0, stream>>>(g, cntb, Wa, ba, Wv, bv, (float*)d_out);
}

// Round 9
// 1009.040 us; speedup vs baseline: 1.0583x; 1.0054x over previous
//
#include <hip/hip_runtime.h>
#include <hip/hip_bf16.h>

// GAT 3-layer + pool + dense head for MI355X (gfx950).
// R2-R10 history: agg kernels are row-rate-capped (~6.8G random 512B rows/s,
// ~6.4G @1KB) — 131us each = 95% of that floor; ale made position-indexed
// (R10, -44MB FETCH, -12us/agg). Aggs are DONE; remaining time is GEMMs +
// ale-GEMM gather + CSR build + dispatch gaps (~620us total).
// R11: GEMM staging package.
//  - global_load_lds width=16 staging for all-bf16 GEMMs (m97 lever), with
//    XOR col swizzle (cb ^= ((r>>1)&3)<<4) applied BOTH on the global source
//    col (stage side) and the ds_read addr (consume side); unpadded [64][32]
//    LDS, b128 reads stay ~2-way (free).
//  - x pre-converted to bf16 once (L1 stops re-reading 154MB f32 + per-tile
//    f2b); all main GEMMs now take the !A_F32 fast path.
//  - ale GEMM keeps reg-staged f32 gather (row-rate-bound anyway) but writes
//    the swizzled LDS layout so the MFMA read path is shared.

typedef __attribute__((ext_vector_type(8))) short short8;
typedef __attribute__((ext_vector_type(4))) float floatx4;
typedef __attribute__((ext_vector_type(4))) unsigned int uintx4;

#define DEV __device__ __forceinline__

DEV unsigned short f2b(float f) {
  union { float f; unsigned u; } v; v.f = f;
  unsigned r = v.u + 0x7FFFu + ((v.u >> 16) & 1u);  // RNE
  return (unsigned short)(r >> 16);
}
DEV float b2f(unsigned short u) {
  union { unsigned u; float f; } v; v.u = ((unsigned)u) << 16;
  return v.f;
}

// ---------------- f32 -> bf16 bulk convert (n divisible by 8) ----------------
__global__ void k_cvt(const float* __restrict__ in, unsigned short* __restrict__ out,
                      int n8) {
  int i = blockIdx.x * 256 + threadIdx.x;
  if (i >= n8) return;
  const float4* p = (const float4*)(in + (size_t)i * 8);
  float4 a = p[0], b = p[1];
  unsigned short t[8];
  t[0]=f2b(a.x); t[1]=f2b(a.y); t[2]=f2b(a.z); t[3]=f2b(a.w);
  t[4]=f2b(b.x); t[5]=f2b(b.y); t[6]=f2b(b.z); t[7]=f2b(b.w);
  *(uint4*)(out + (size_t)i * 8) = *(uint4*)t;
}

// ---------------- bucketed CSR build ----------------
// deg2[n*8 + b] = #edges into n with src in bucket b (b = src>>13, 0..6).
__global__ void k_deg2(const int* __restrict__ src, const int* __restrict__ dst,
                       int* __restrict__ deg2, int E) {
  int e = blockIdx.x * 256 + threadIdx.x;
  if (e < E) atomicAdd(&deg2[(size_t)dst[e] * 8 + (src[e] >> 13)], 1);
}

// block-local exclusive scan over 1024 elems (256 thr x 4)
__global__ __launch_bounds__(256) void k_scan1(const int* __restrict__ deg,
    int* __restrict__ rowptr, int* __restrict__ bsum, int N) {
  __shared__ int sd[256];
  int b = blockIdx.x, tid = threadIdx.x;
  int i0 = b * 1024 + tid * 4;
  int v[4]; int s = 0;
#pragma unroll
  for (int j = 0; j < 4; j++) { int i = i0 + j; v[j] = (i < N) ? deg[i] : 0; s += v[j]; }
  sd[tid] = s;
  __syncthreads();
  for (int off = 1; off < 256; off <<= 1) {
    int t = (tid >= off) ? sd[tid - off] : 0;
    __syncthreads();
    sd[tid] += t;
    __syncthreads();
  }
  int run = sd[tid] - s;  // exclusive
#pragma unroll
  for (int j = 0; j < 4; j++) { int i = i0 + j; if (i < N) rowptr[i] = run; run += v[j]; }
  if (tid == 255) bsum[b] = sd[255];
}

// scan over up to 512 block sums
__global__ __launch_bounds__(512) void k_scan2(int* __restrict__ bsum, int nb) {
  __shared__ int sd[512];
  int tid = threadIdx.x;
  int v = (tid < nb) ? bsum[tid] : 0;
  sd[tid] = v;
  __syncthreads();
  for (int off = 1; off < 512; off <<= 1) {
    int t = (tid >= off) ? sd[tid - off] : 0;
    __syncthreads();
    sd[tid] += t;
    __syncthreads();
  }
  if (tid < nb) bsum[tid] = sd[tid] - v;  // exclusive
}

__global__ __launch_bounds__(256) void k_scan3(int* __restrict__ rowptr,
    int* __restrict__ cursor, const int* __restrict__ bsum, int N, int E) {
  int b = blockIdx.x, tid = threadIdx.x;
  int add = bsum[b];
  int i0 = b * 1024 + tid * 4;
#pragma unroll
  for (int j = 0; j < 4; j++) {
    int i = i0 + j;
    if (i < N) { int r = rowptr[i] + add; rowptr[i] = r; cursor[i] = r; }
  }
  if (b == 0 && tid == 0) rowptr[N] = E;
}

__global__ void k_scatter(const int* __restrict__ src, const int* __restrict__ dst,
    int* __restrict__ cursor, int2* __restrict__ csr, int E) {
  int e = blockIdx.x * 256 + threadIdx.x;
  if (e < E) {
    int s = src[e], d = dst[e];
    int pos = atomicAdd(&cursor[(size_t)d * 8 + (s >> 13)], 1);
    csr[pos] = make_int2(s, e);
  }
}

// ---------------- weight prep ----------------
__global__ void k_wt(const float* __restrict__ W, unsigned short* __restrict__ Wt,
                     int K, int Nout) {
  int idx = blockIdx.x * 256 + threadIdx.x;
  if (idx < K * Nout) {
    int n = idx / K, k = idx - n * K;
    Wt[idx] = f2b(W[(size_t)k * Nout + n]);
  }
}

// Wept[j][c], j = L*4+h (12 rows used, 16 total)
__global__ void k_wep(const float* __restrict__ We1, const float* __restrict__ ae1,
                      const float* __restrict__ We2, const float* __restrict__ ae2,
                      const float* __restrict__ We3, const float* __restrict__ ae3,
                      unsigned short* __restrict__ Wept) {
  int t = blockIdx.x * 256 + threadIdx.x;  // 0..767
  int j = t >> 6, c = t & 63;
  int L = j >> 2, h = j & 3;
  const float* We = (L == 0) ? We1 : (L == 1) ? We2 : We3;
  const float* ae = (L == 0) ? ae1 : (L == 1) ? ae2 : ae3;
  int C = (L == 2) ? 128 : 64;
  int HC = 4 * C;
  float s = 0.f;
  for (int cc = 0; cc < C; cc++) s += We[(size_t)c * HC + h * C + cc] * ae[h * C + cc];
  Wept[j * 64 + c] = f2b(s);
  if (t < 256) {
    int jj = 12 + (t >> 6);
    Wept[jj * 64 + (t & 63)] = 0;
  }
}

// ---------------- GEMM: C[M,Nout] = A[M,K] @ Bt[Nout,K]^T ----------------
// LDS: unpadded [64][32] shorts, XOR-swizzled: LDS[r][c] holds A[r][c ^ swz(r)]
// where swz(r) byte-XOR = ((r>>1)&3)<<4. !A_F32: staged via global_load_lds
// (pre-swizzled global source col). A_F32 (ale GEMM): reg-staged f2b +
// swizzled ds_write; A row gathered via eidmap[gm].y (position-indexed out).
// OUT_MODE: 0 = bf16 C; 2 = ale position-major f32 ([L][EN][4], col<12)
// DO_ALD: epilogue also accumulates als/ald (head = n0*4/Nout, uniform/block)
template<bool A_F32, int OUT_MODE, bool DO_ALD>
__global__ __launch_bounds__(256) void k_gemm(const void* __restrict__ Ap,
    const unsigned short* __restrict__ Bt, void* __restrict__ Cp,
    int M, int Nout, int K, int EN,
    const float* __restrict__ a_s, const float* __restrict__ a_d,
    float* __restrict__ als, float* __restrict__ ald,
    const int2* __restrict__ eidmap) {
  __shared__ unsigned short As[64][32];
  __shared__ unsigned short Bs[64][32];
  const int tid = threadIdx.x;
  const int wave = tid >> 6, lane = tid & 63;
  const int quad = lane >> 4, l16 = lane & 15;
  const int m0 = blockIdx.x * 64, n0 = blockIdx.y * 64;
  const int arow = tid >> 2;            // staged tile row
  const int cb0  = (tid & 3) << 4;      // unswizzled col byte (0..48)
  const int swzr = ((arow >> 1) & 3) << 4;
  floatx4 acc[4] = {{0,0,0,0},{0,0,0,0},{0,0,0,0},{0,0,0,0}};
  for (int k0 = 0; k0 < K; k0 += 32) {
    if (A_F32) {
      // reg staging + swizzled ds_write (ale GEMM: gather f32 rows, Nout<64)
      int gm = m0 + arow;
      unsigned short tmp[8];
      if (gm < M) {
        size_t ar = (size_t)gm;
        if (OUT_MODE == 2) ar = (size_t)eidmap[gm].y;
        const float* Af = (const float*)Ap;
        const float4* p = (const float4*)(Af + ar * K + k0 + (cb0 >> 1));
        float4 u0 = p[0], u1 = p[1];
        tmp[0]=f2b(u0.x); tmp[1]=f2b(u0.y); tmp[2]=f2b(u0.z); tmp[3]=f2b(u0.w);
        tmp[4]=f2b(u1.x); tmp[5]=f2b(u1.y); tmp[6]=f2b(u1.z); tmp[7]=f2b(u1.w);
      } else {
#pragma unroll
        for (int j = 0; j < 8; j++) tmp[j] = 0;
      }
      *(uint4*)((char*)&As[0][0] + arow * 64 + (cb0 ^ swzr)) = *(uint4*)tmp;
      int gn = n0 + arow;
      uint4 bv = {0,0,0,0};
      if (gn < Nout) bv = *(const uint4*)(Bt + (size_t)gn * K + k0 + (cb0 >> 1));
      *(uint4*)((char*)&Bs[0][0] + arow * 64 + (cb0 ^ swzr)) = bv;
    } else {
      // global_load_lds: dest = wave-uniform base + lane*16 (linear);
      // swizzle applied on the GLOBAL source column instead.
      int gm = m0 + arow; if (gm >= M) gm = M - 1;  // clamp; rows>=M never stored
      int cbs = cb0 ^ swzr;
      const unsigned short* gA =
          (const unsigned short*)Ap + (size_t)gm * K + k0 + (cbs >> 1);
      __builtin_amdgcn_global_load_lds(gA, (char*)&As[0][0] + wave * 1024, 16, 0, 0);
      int gn = n0 + arow;  // Nout multiple of 64 on this path
      const unsigned short* gB = Bt + (size_t)gn * K + k0 + (cbs >> 1);
      __builtin_amdgcn_global_load_lds(gB, (char*)&Bs[0][0] + wave * 1024, 16, 0, 0);
    }
    __syncthreads();
    int ra = wave * 16 + l16;
    short8 a = *(const short8*)((const char*)&As[0][0] + ra * 64 +
                                ((quad * 16) ^ (((ra >> 1) & 3) << 4)));
#pragma unroll
    for (int t = 0; t < 4; t++) {
      int rb = t * 16 + l16;
      short8 b = *(const short8*)((const char*)&Bs[0][0] + rb * 64 +
                                  ((quad * 16) ^ (((rb >> 1) & 3) << 4)));
      acc[t] = __builtin_amdgcn_mfma_f32_16x16x32_bf16(a, b, acc[t], 0, 0, 0);
    }
    __syncthreads();
  }
#pragma unroll
  for (int t = 0; t < 4; t++) {
#pragma unroll
    for (int r = 0; r < 4; r++) {
      int row = m0 + wave * 16 + quad * 4 + r;  // C/D: col=lane&15, row=quad*4+reg
      int col = n0 + t * 16 + l16;
      float v = acc[t][r];
      if (OUT_MODE == 0) {
        if (row < M && col < Nout)
          ((unsigned short*)Cp)[(size_t)row * Nout + col] = f2b(v);
      } else {  // ale position-major
        if (row < M && col < 12)
          ((float*)Cp)[((size_t)(col >> 2) * EN + row) * 4 + (col & 3)] = v;
      }
    }
  }
  if constexpr (DO_ALD) {
    int h = (n0 * 4) / Nout;
#pragma unroll
    for (int r = 0; r < 4; r++) {
      float ps = 0.f, pd = 0.f;
#pragma unroll
      for (int t = 0; t < 4; t++) {
        int col = n0 + t * 16 + l16;
        float v = acc[t][r];
        ps += v * a_s[col];
        pd += v * a_d[col];
      }
#pragma unroll
      for (int off = 1; off < 16; off <<= 1) {
        ps += __shfl_xor(ps, off, 64);
        pd += __shfl_xor(pd, off, 64);
      }
      int row = m0 + wave * 16 + quad * 4 + r;
      if (l16 == 0 && row < M) {
        atomicAdd(&als[row * 4 + h], ps);
        atomicAdd(&ald[row * 4 + h], pd);
      }
    }
  }
}

// ---------------- self-loop al_e = mean of incoming al_e ----------------
// rowptr2 is [N*8+1]; node n's range = [rowptr2[8n], rowptr2[8n+8]).
// ale is position-indexed: contiguous read per node.
__global__ void k_loop_ale(const int* __restrict__ rowptr2,
                           float* __restrict__ ale, int N, int E) {
  int n = blockIdx.x * 256 + threadIdx.x;
  if (n >= N) return;
  const size_t EN = (size_t)E + N;
  int s = rowptr2[(size_t)n * 8], e = rowptr2[(size_t)n * 8 + 8];
  float a[12];
#pragma unroll
  for (int j = 0; j < 12; j++) a[j] = 0.f;
  for (int p = s; p < e; p++) {
#pragma unroll
    for (int L = 0; L < 3; L++) {
      float4 v = *(const float4*)(ale + (L * EN + p) * 4);
      a[L * 4 + 0] += v.x; a[L * 4 + 1] += v.y;
      a[L * 4 + 2] += v.z; a[L * 4 + 3] += v.w;
    }
  }
  float inv = 1.0f / (float)((e - s) > 1 ? (e - s) : 1);
#pragma unroll
  for (int L = 0; L < 3; L++)
    *(float4*)(ale + (L * EN + E + n) * 4) =
        make_float4(a[L*4+0]*inv, a[L*4+1]*inv, a[L*4+2]*inv, a[L*4+3]*inv);
}

// ---------------- CSR online-softmax aggregation ----------------
// LPN lanes per node (8 for HC=256, 16 for HC=512), FPL=32 features/lane.
// ale position-indexed => alpha phase is csr(seq)+ale(seq)+als(L2-resident);
// the only random stream is the hs row gather (row-rate-capped, ~95% of
// floor per R10 PMC). rowptr2: node range = [rowptr2[8n], rowptr2[8n+8]).
// MODE 0: concat+bias+ReLU -> bf16. MODE 1: mean+bias -> f32.
template<int LPN, int MODE>
__global__ __launch_bounds__(256) void k_agg(const unsigned short* __restrict__ hs,
    const int* __restrict__ rowptr2, const int2* __restrict__ csr,
    const float* __restrict__ ale,  // layer base, [EN][4], position-indexed
    const float* __restrict__ als, const float* __restrict__ ald,
    const float* __restrict__ bias, unsigned short* __restrict__ outb,
    float* __restrict__ outf, int N, int E) {
  const int FPL = 32;
  const int HC  = LPN * FPL;   // row width in shorts
  const int NG  = 64 / LPN;    // nodes per wave
  __shared__ float s_w[4][NG][LPN][4];
  __shared__ int   s_s[4][NG][LPN];
  const int wave = threadIdx.x >> 6;
  const int lane = threadIdx.x & 63;
  const int grp  = lane / LPN;
  const int sl   = lane % LPN;
  const int hd   = sl >> (LPN >> 3);  // head owning this lane's feature slice
  const int node = blockIdx.x * (4 * NG) + wave * NG + grp;
  if (node >= N) return;  // no __syncthreads in this kernel
  int start = rowptr2[(size_t)node * 8];
  int cnt   = rowptr2[(size_t)node * 8 + 8] - start;
  int total = cnt + 1;  // + self-loop
  const float4 aldv   = *(const float4*)(ald + (size_t)node * 4);
  const float4 selfev = *(const float4*)(ale + ((size_t)E + node) * 4);
  const float4 selfsv = *(const float4*)(als + (size_t)node * 4);
  // prefetch chunk 0's alpha inputs
  int    psidx = node;
  float4 pev = selfev, psv = selfsv;
  if (sl < cnt) {
    int2 se = csr[start + sl];
    psidx = se.x;
    pev = *(const float4*)(ale + (size_t)(start + sl) * 4);
    psv = *(const float4*)(als + (size_t)se.x * 4);
  }
  float m0=-1e30f, m1=-1e30f, m2=-1e30f, m3=-1e30f;
  float d0=0.f, d1=0.f, d2=0.f, d3=0.f;
  float acc[FPL];
#pragma unroll
  for (int j = 0; j < FPL; j++) acc[j] = 0.f;
  for (int base = 0; base < total; base += LPN) {
    int ei = base + sl;
    bool active = ei < total;
    float a0=-1e30f, a1=-1e30f, a2=-1e30f, a3=-1e30f;
    int sidx = psidx;
    if (active) {
      a0 = psv.x + aldv.x + pev.x;
      a1 = psv.y + aldv.y + pev.y;
      a2 = psv.z + aldv.z + pev.z;
      a3 = psv.w + aldv.w + pev.w;
      a0 = a0 > 0.f ? a0 : 0.2f * a0;
      a1 = a1 > 0.f ? a1 : 0.2f * a1;
      a2 = a2 > 0.f ? a2 : 0.2f * a2;
      a3 = a3 > 0.f ? a3 : 0.2f * a3;
    }
    float c0=a0, c1=a1, c2=a2, c3=a3;
#pragma unroll
    for (int off = LPN / 2; off > 0; off >>= 1) {
      c0 = fmaxf(c0, __shfl_xor(c0, off, 64));
      c1 = fmaxf(c1, __shfl_xor(c1, off, 64));
      c2 = fmaxf(c2, __shfl_xor(c2, off, 64));
      c3 = fmaxf(c3, __shfl_xor(c3, off, 64));
    }
    float n0v = fmaxf(m0, c0), n1v = fmaxf(m1, c1), n2v = fmaxf(m2, c2), n3v = fmaxf(m3, c3);
    float p0 = active ? __expf(a0 - n0v) : 0.f;
    float p1 = active ? __expf(a1 - n1v) : 0.f;
    float p2 = active ? __expf(a2 - n2v) : 0.f;
    float p3 = active ? __expf(a3 - n3v) : 0.f;
    float s0=p0, s1=p1, s2=p2, s3=p3;
#pragma unroll
    for (int off = LPN / 2; off > 0; off >>= 1) {
      s0 += __shfl_xor(s0, off, 64);
      s1 += __shfl_xor(s1, off, 64);
      s2 += __shfl_xor(s2, off, 64);
      s3 += __shfl_xor(s3, off, 64);
    }
    float r0 = __expf(m0 - n0v), r1 = __expf(m1 - n1v);
    float r2 = __expf(m2 - n2v), r3 = __expf(m3 - n3v);
    d0 = d0 * r0 + s0; d1 = d1 * r1 + s1; d2 = d2 * r2 + s2; d3 = d3 * r3 + s3;
    float rh = hd == 0 ? r0 : hd == 1 ? r1 : hd == 2 ? r2 : r3;
#pragma unroll
    for (int j = 0; j < FPL; j++) acc[j] *= rh;
    m0 = n0v; m1 = n1v; m2 = n2v; m3 = n3v;
    *(float4*)&s_w[wave][grp][sl][0] = make_float4(p0, p1, p2, p3);
    s_s[wave][grp][sl] = sidx;
    __threadfence_block();  // per-wave LDS visibility
    // prefetch next chunk's alpha inputs (in flight during gather below)
    if (base + LPN < total) {
      int nei = base + LPN + sl;
      psidx = node; pev = selfev; psv = selfsv;
      if (nei < cnt) {
        int2 se = csr[start + nei];
        psidx = se.x;
        pev = *(const float4*)(ale + (size_t)(start + nei) * 4);
        psv = *(const float4*)(als + (size_t)se.x * 4);
      }
    }
    int chunk = total - base; if (chunk > LPN) chunk = LPN;
    int t = 0;
    // 2 edges x 4 dwordx4 pinned in flight via asm operand list.
    for (; t + 2 <= chunk; t += 2) {
      float w0 = s_w[wave][grp][t][hd];
      float w1 = s_w[wave][grp][t + 1][hd];
      int   q0 = s_s[wave][grp][t];
      int   q1 = s_s[wave][grp][t + 1];
      const uintx4* p0p = (const uintx4*)(hs + (size_t)q0 * HC + sl * FPL);
      const uintx4* p1p = (const uintx4*)(hs + (size_t)q1 * HC + sl * FPL);
      uintx4 v0[4], v1[4];
#pragma unroll
      for (int q = 0; q < 4; q++) v0[q] = p0p[q];
#pragma unroll
      for (int q = 0; q < 4; q++) v1[q] = p1p[q];
      asm volatile("" :: "v"(v0[0]), "v"(v0[1]), "v"(v0[2]), "v"(v0[3]),
                         "v"(v1[0]), "v"(v1[1]), "v"(v1[2]), "v"(v1[3]));
#pragma unroll
      for (int q = 0; q < 4; q++) {
        uintx4 x = v0[q];
#pragma unroll
        for (int k = 0; k < 4; k++) {
          float lo = __uint_as_float(x[k] << 16);
          float hi = __uint_as_float(x[k] & 0xffff0000u);
          acc[q * 8 + k * 2 + 0] += w0 * lo;
          acc[q * 8 + k * 2 + 1] += w0 * hi;
        }
      }
#pragma unroll
      for (int q = 0; q < 4; q++) {
        uintx4 x = v1[q];
#pragma unroll
        for (int k = 0; k < 4; k++) {
          float lo = __uint_as_float(x[k] << 16);
          float hi = __uint_as_float(x[k] & 0xffff0000u);
          acc[q * 8 + k * 2 + 0] += w1 * lo;
          acc[q * 8 + k * 2 + 1] += w1 * hi;
        }
      }
    }
    if (t < chunk) {
      float w0 = s_w[wave][grp][t][hd];
      int   q0 = s_s[wave][grp][t];
      const uintx4* p0p = (const uintx4*)(hs + (size_t)q0 * HC + sl * FPL);
      uintx4 v0[4];
#pragma unroll
      for (int q = 0; q < 4; q++) v0[q] = p0p[q];
#pragma unroll
      for (int q = 0; q < 4; q++) {
        uintx4 x = v0[q];
#pragma unroll
        for (int k = 0; k < 4; k++) {
          float lo = __uint_as_float(x[k] << 16);
          float hi = __uint_as_float(x[k] & 0xffff0000u);
          acc[q * 8 + k * 2 + 0] += w0 * lo;
          acc[q * 8 + k * 2 + 1] += w0 * hi;
        }
      }
    }
  }
  float dh = hd == 0 ? d0 : hd == 1 ? d1 : hd == 2 ? d2 : d3;
  float inv = 1.0f / (dh + 1e-16f);
  if constexpr (MODE == 0) {
    unsigned short tmp[FPL];
#pragma unroll
    for (int j = 0; j < FPL; j++) {
      float v = acc[j] * inv + bias[sl * FPL + j];
      tmp[j] = f2b(fmaxf(v, 0.f));
    }
    unsigned short* op = outb + (size_t)node * HC + sl * FPL;
#pragma unroll
    for (int q = 0; q < 4; q++) ((uint4*)op)[q] = ((uint4*)tmp)[q];
  } else {
    // mean over heads (LPN=16): lane sl covers hs cols [sl*32, sl*32+32);
    // head=sl>>2, out col c = (sl&3)*32 + j. Sum lanes sl^4, sl^8.
#pragma unroll
    for (int j = 0; j < FPL; j++) {
      float v = acc[j] * inv;
      v += __shfl_xor(v, 4, 64);
      v += __shfl_xor(v, 8, 64);
      acc[j] = v * 0.25f;
    }
    if (sl < 4) {
      float* op = outf + (size_t)node * (4 * FPL) + sl * FPL;
#pragma unroll
      for (int j = 0; j < FPL; j++) op[j] = acc[j] + bias[sl * FPL + j];
    }
  }
}

// ---------------- pooling (batch is sorted) ----------------
__global__ __launch_bounds__(256) void k_pool(const float* __restrict__ out3,
    const int* __restrict__ bat, float* __restrict__ g, int* __restrict__ cntb, int N) {
  int wid = blockIdx.x * 4 + (threadIdx.x >> 6);
  int lane = threadIdx.x & 63;
  int per = (N + 255) / 256;
  int s = wid * per, e = s + per;
  if (e > N) e = N;
  if (s >= e) return;
  int cur = bat[s];
  float ax = 0.f, ay = 0.f; int run = 0;
  for (int n = s; n < e; n++) {
    int b = bat[n];
    if (b != cur) {
      atomicAdd(&g[cur * 128 + lane * 2], ax);
      atomicAdd(&g[cur * 128 + lane * 2 + 1], ay);
      if (lane == 0) atomicAdd(&cntb[cur], run);
      ax = 0.f; ay = 0.f; run = 0; cur = b;
    }
    float2 v = *(const float2*)(out3 + (size_t)n * 128 + lane * 2);
    ax += v.x; ay += v.y; run++;
  }
  atomicAdd(&g[cur * 128 + lane * 2], ax);
  atomicAdd(&g[cur * 128 + lane * 2 + 1], ay);
  if (lane == 0) atomicAdd(&cntb[cur], run);
}

// ---------------- final head ----------------
__global__ __launch_bounds__(320) void k_final(const float* __restrict__ g,
    const int* __restrict__ cntb, const float* __restrict__ Wa, const float* __restrict__ ba,
    const float* __restrict__ Wv, const float* __restrict__ bv, float* __restrict__ out) {
  __shared__ float gm[128];
  int b = blockIdx.x, t = threadIdx.x;
  if (t < 128) {
    float c = (float)cntb[b];
    gm[t] = g[b * 128 + t] / fmaxf(c, 1.f);
  }
  __syncthreads();
  if (t < 257) {
    float acc = 0.f;
    if (t < 256) {
      for (int k = 0; k < 128; k++) acc += gm[k] * Wa[k * 256 + t];
      acc += ba[t];
    } else {
      for (int k = 0; k < 128; k++) acc += gm[k] * Wv[k];
      acc += bv[0];
    }
    out[b * 257 + t] = acc;
  }
}

extern "C" void kernel_launch(void* const* d_in, const int* in_sizes, int n_in,
                              void* d_out, int out_size, void* d_ws, size_t ws_size,
                              hipStream_t stream) {
  const float* x   = (const float*)d_in[0];
  const int*   ei  = (const int*)  d_in[1];
  const float* ea  = (const float*)d_in[2];
  const int*   bat = (const int*)  d_in[3];
  const float* W1  = (const float*)d_in[4];
  const float* as1 = (const float*)d_in[5];
  const float* ad1 = (const float*)d_in[6];
  const float* We1 = (const float*)d_in[7];
  const float* ae1 = (const float*)d_in[8];
  const float* b1  = (const float*)d_in[9];
  const float* W2  = (const float*)d_in[10];
  const float* as2 = (const float*)d_in[11];
  const float* ad2 = (const float*)d_in[12];
  const float* We2 = (const float*)d_in[13];
  const float* ae2 = (const float*)d_in[14];
  const float* b2  = (const float*)d_in[15];
  const float* W3  = (const float*)d_in[16];
  const float* as3 = (const float*)d_in[17];
  const float* ad3 = (const float*)d_in[18];
  const float* We3 = (const float*)d_in[19];
  const float* ae3 = (const float*)d_in[20];
  const float* b3  = (const float*)d_in[21];
  const float* Wa  = (const float*)d_in[22];
  const float* ba  = (const float*)d_in[23];
  const float* Wv  = (const float*)d_in[24];
  const float* bv  = (const float*)d_in[25];
  (void)n_in; (void)out_size; (void)ws_size;

  const int N = in_sizes[0] / 192;  // 50000
  const int E = in_sizes[1] / 2;    // 800000
  const size_t EN = (size_t)E + N;
  const int* srcv = ei;
  const int* dstv = ei + E;
  const int N2 = N * 8;                      // bucketed rowptr length
  const int nbB = (N2 + 1023) / 1024;        // scan blocks over N2 (<=512)

  size_t off = 0;
  auto alloc = [&](size_t bytes) -> char* {
    char* p = (char*)d_ws + off;
    off += (bytes + 255) & ~(size_t)255;
    return p;
  };
  int* deg2    = (int*)alloc((size_t)N2 * 4);
  int* rowptr2 = (int*)alloc((size_t)(N2 + 1) * 4);
  int* cursor2 = (int*)alloc((size_t)N2 * 4);
  int* bsum    = (int*)alloc(512 * 4);
  int2* csr    = (int2*)alloc((size_t)E * 8);
  float* ale   = (float*)alloc(3 * EN * 4 * 4);  // [L][EN][4], position-indexed
  unsigned short* Wept = (unsigned short*)alloc(16 * 64 * 2);
  unsigned short* W1t  = (unsigned short*)alloc(256 * 192 * 2);
  unsigned short* W2t  = (unsigned short*)alloc(256 * 256 * 2);
  unsigned short* W3t  = (unsigned short*)alloc(512 * 256 * 2);
  unsigned short* xB   = (unsigned short*)alloc((size_t)N * 192 * 2);
  unsigned short* hs   = (unsigned short*)alloc((size_t)N * 512 * 2);
  unsigned short* h1   = (unsigned short*)alloc((size_t)N * 256 * 2);
  unsigned short* h2   = (unsigned short*)alloc((size_t)N * 256 * 2);
  float* out3  = (float*)alloc((size_t)N * 128 * 4);
  float* als_all = (float*)alloc((size_t)N * 4 * 4 * 6);  // als1,ald1,als2,ald2,als3,ald3
  float* g     = (float*)alloc(64 * 128 * 4 + 64 * 4);
  int* cntb    = (int*)(g + 64 * 128);
  float* als1 = als_all + (size_t)N * 4 * 0;
  float* ald1 = als_all + (size_t)N * 4 * 1;
  float* als2 = als_all + (size_t)N * 4 * 2;
  float* ald2 = als_all + (size_t)N * 4 * 3;
  float* als3 = als_all + (size_t)N * 4 * 4;
  float* ald3 = als_all + (size_t)N * 4 * 5;

  hipMemsetAsync(deg2, 0, (size_t)N2 * 4, stream);
  hipMemsetAsync(als_all, 0, (size_t)N * 4 * 4 * 6, stream);
  hipMemsetAsync(g, 0, 64 * 128 * 4 + 64 * 4, stream);

  k_deg2<<<(E + 255) / 256, 256, 0, stream>>>(srcv, dstv, deg2, E);
  k_scan1<<<nbB, 256, 0, stream>>>(deg2, rowptr2, bsum, N2);
  k_scan2<<<1, 512, 0, stream>>>(bsum, nbB);
  k_scan3<<<nbB, 256, 0, stream>>>(rowptr2, cursor2, bsum, N2, E);
  k_scatter<<<(E + 255) / 256, 256, 0, stream>>>(srcv, dstv, cursor2, csr, E);
  k_cvt<<<((N * 192 / 8) + 255) / 256, 256, 0, stream>>>(x, xB, N * 192 / 8);
  k_wt<<<(192 * 256 + 255) / 256, 256, 0, stream>>>(W1, W1t, 192, 256);
  k_wt<<<(256 * 256 + 255) / 256, 256, 0, stream>>>(W2, W2t, 256, 256);
  k_wt<<<(256 * 512 + 255) / 256, 256, 0, stream>>>(W3, W3t, 256, 512);
  k_wep<<<3, 256, 0, stream>>>(We1, ae1, We2, ae2, We3, ae3, Wept);
  // al_e for all 3 layers in one GEMM over edge_attr, A gathered via csr[pos].y
  // so the output is position-indexed (sequential for all later readers).
  k_gemm<true, 2, false><<<dim3((E + 63) / 64, 1), 256, 0, stream>>>(
      ea, Wept, ale, E, 16, 64, (int)EN, nullptr, nullptr, nullptr, nullptr, csr);
  k_loop_ale<<<(N + 255) / 256, 256, 0, stream>>>(rowptr2, ale, N, E);
  // layer 1 (A now bf16 via xB -> global_load_lds fast path)
  k_gemm<false, 0, true><<<dim3((N + 63) / 64, 4), 256, 0, stream>>>(
      xB, W1t, hs, N, 256, 192, 0, as1, ad1, als1, ald1, nullptr);
  k_agg<8, 0><<<(N + 31) / 32, 256, 0, stream>>>(
      hs, rowptr2, csr, ale + 0 * EN * 4, als1, ald1, b1, h1, nullptr, N, E);
  // layer 2
  k_gemm<false, 0, true><<<dim3((N + 63) / 64, 4), 256, 0, stream>>>(
      h1, W2t, hs, N, 256, 256, 0, as2, ad2, als2, ald2, nullptr);
  k_agg<8, 0><<<(N + 31) / 32, 256, 0, stream>>>(
      hs, rowptr2, csr, ale + 1 * EN * 4, als2, ald2, b2, h2, nullptr, N, E);
  // layer 3
  k_gemm<false, 0, true><<<dim3((N + 63) / 64, 8), 256, 0, stream>>>(
      h2, W3t, hs, N, 512, 256, 0, as3, ad3, als3, ald3, nullptr);
  k_agg<16, 1><<<(N + 15) / 16, 256, 0, stream>>>(
      hs, rowptr2, csr, ale + 2 * EN * 4, als3, ald3, b3, nullptr, out3, N, E);
  // pool + head
  k_pool<<<64, 256, 0, stream>>>(out3, bat, g, cntb, N);
  k_final<<<64, 320, 0, stream>>>(g, cntb, Wa, ba, Wv, bv, (float*)d_out);
}